// Round 5
// baseline (687.806 us; speedup 1.0000x reference)
//
#include <hip/hip_runtime.h>
#include <hip/hip_bf16.h>

#define NEG_SLOPE 0.2f

typedef __attribute__((ext_vector_type(8))) short bf16x8;
typedef __attribute__((ext_vector_type(4))) float f32x4;

__device__ __forceinline__ unsigned short f2bf(float v) {
    union { float f; unsigned int u; } x; x.f = v;
    unsigned int r = x.u + 0x7fffu + ((x.u >> 16) & 1u);
    return (unsigned short)(r >> 16);
}
__device__ __forceinline__ float bf2f(unsigned short b) {
    union { unsigned int u; float f; } x; x.u = ((unsigned int)b) << 16;
    return x.f;
}

// ---------------- CSR build ----------------

__global__ void count_edges_k(const int* __restrict__ ei, int E, int n, int* __restrict__ cnt) {
    int e = blockIdx.x * 256 + threadIdx.x;
    int ET = E + n;
    if (e >= ET) return;
    int d = (e < E) ? ei[E + e] : (e - E);
    atomicAdd(&cnt[d], 1);
}

__global__ void scan1_k(const int* __restrict__ cnt, int* __restrict__ row_ptr,
                        int* __restrict__ bsums, int n) {
    __shared__ int sd[256];
    int b = blockIdx.x, t = threadIdx.x;
    int base = b * 1024 + t * 4;
    int v[4];
    int loc = 0;
#pragma unroll
    for (int j = 0; j < 4; ++j) {
        v[j] = (base + j < n) ? cnt[base + j] : 0;
        loc += v[j];
    }
    sd[t] = loc;
    __syncthreads();
    for (int off = 1; off < 256; off <<= 1) {
        int x = (t >= off) ? sd[t - off] : 0;
        __syncthreads();
        sd[t] += x;
        __syncthreads();
    }
    int run = sd[t] - loc;
    if (t == 255) bsums[b] = sd[t];
#pragma unroll
    for (int j = 0; j < 4; ++j) {
        if (base + j < n) row_ptr[base + j] = run;
        run += v[j];
    }
}

__global__ void scan2_k(int* __restrict__ bsums, int nb) {
    if (threadIdx.x == 0 && blockIdx.x == 0) {
        int run = 0;
        for (int i = 0; i < nb; ++i) { int x = bsums[i]; bsums[i] = run; run += x; }
    }
}

__global__ void scan3_k(int* __restrict__ row_ptr, int* __restrict__ pos,
                        const int* __restrict__ bsums, int n, int total) {
    int idx = blockIdx.x * 256 + threadIdx.x;
    if (idx < n) {
        int vv = row_ptr[idx] + bsums[idx >> 10];
        row_ptr[idx] = vv;
        pos[idx] = vv;
    } else if (idx == n) {
        row_ptr[n] = total;
    }
}

__global__ void scatter_edges_k(const int* __restrict__ ei, int E, int n,
                                int* __restrict__ pos, int* __restrict__ srcs) {
    int e = blockIdx.x * 256 + threadIdx.x;
    int ET = E + n;
    if (e >= ET) return;
    int s, d;
    if (e < E) { s = ei[e]; d = ei[E + e]; }
    else       { s = e - E; d = e - E; }
    int idx = atomicAdd(&pos[d], 1);
    srcs[idx] = s;
}

// ---------------- weight pre-convert ----------------

// W[K][Nc] fp32 -> col-major hi/lo bf16 [Nc][K]
__global__ void convert_w_k(const float* __restrict__ W,
                            unsigned short* __restrict__ Bh, unsigned short* __restrict__ Bl,
                            int K, int Nc) {
    int idx = blockIdx.x * 256 + threadIdx.x;
    if (idx >= K * Nc) return;
    int k = idx / Nc, c = idx - k * Nc;
    float v = W[idx];
    unsigned short h = f2bf(v);
    float r = v - bf2f(h);
    Bh[c * K + k] = h;
    Bl[c * K + k] = f2bf(r);
}

// W3[K][40] fp32 -> col-major hi/lo bf16 [c][K] (cols 40..127 pre-zeroed by memset)
__global__ void convert_w3_k(const float* __restrict__ W,
                             unsigned short* __restrict__ Bh, unsigned short* __restrict__ Bl,
                             int K, int Nc) {
    int idx = blockIdx.x * 256 + threadIdx.x;
    if (idx >= K * Nc) return;
    int k = idx / Nc, c = idx - k * Nc;
    float v = W[idx];
    unsigned short h = f2bf(v);
    float r = v - bf2f(h);
    Bh[c * K + k] = h;
    Bl[c * K + k] = f2bf(r);
}

// ---------------- split-bf16 MFMA GEMM -> bf16 output ----------------
// A fp32 row-major; W pre-converted Bh/Bl bf16 col-major [Nc][K]; C bf16 row-major [M][Nc].
// block = 256 thr (4 waves), tile 128x128, wave tile 64x64, K-step 32.

#define GPAD 40

__global__ __launch_bounds__(256) void mfma_gemm_k(const float* __restrict__ A,
                                                   const unsigned short* __restrict__ Bh,
                                                   const unsigned short* __restrict__ Bl,
                                                   unsigned short* __restrict__ Cb,
                                                   int M, int K, int Nc) {
    __shared__ unsigned short Ash[128][GPAD];
    __shared__ unsigned short Asl[128][GPAD];
    __shared__ unsigned short Bsh[128][GPAD];
    __shared__ unsigned short Bsl[128][GPAD];

    int bm = blockIdx.y * 128;
    int bn = blockIdx.x * 128;
    int t = threadIdx.x;
    int w = t >> 6, l = t & 63;
    int wm = w >> 1, wn = w & 1;
    int lr = l & 15, lk = (l >> 4) * 8;

    int srow = t >> 1;
    int skh  = (t & 1) * 16;

    f32x4 acc[4][4];
#pragma unroll
    for (int i = 0; i < 4; ++i)
#pragma unroll
        for (int j = 0; j < 4; ++j)
            acc[i][j] = (f32x4){0.f, 0.f, 0.f, 0.f};

    const int arow = bm + srow;
    const bool arow_ok = (arow < M);
    const size_t acol_base = (size_t)arow * K + skh;
    const size_t bcol_base = (size_t)(bn + srow) * K + skh;

    for (int k0 = 0; k0 < K; k0 += 32) {
        float vv[16];
        if (arow_ok) {
            const float4* ap = reinterpret_cast<const float4*>(A + acol_base + k0);
#pragma unroll
            for (int q = 0; q < 4; ++q) {
                float4 v4 = ap[q];
                vv[4 * q + 0] = v4.x; vv[4 * q + 1] = v4.y;
                vv[4 * q + 2] = v4.z; vv[4 * q + 3] = v4.w;
            }
        } else {
#pragma unroll
            for (int q = 0; q < 16; ++q) vv[q] = 0.f;
        }
        unsigned int hw[8], lw[8];
#pragma unroll
        for (int q = 0; q < 8; ++q) {
            unsigned short h0 = f2bf(vv[2 * q]);
            unsigned short h1 = f2bf(vv[2 * q + 1]);
            unsigned short l0 = f2bf(vv[2 * q] - bf2f(h0));
            unsigned short l1 = f2bf(vv[2 * q + 1] - bf2f(h1));
            hw[q] = (unsigned int)h0 | ((unsigned int)h1 << 16);
            lw[q] = (unsigned int)l0 | ((unsigned int)l1 << 16);
        }
        __syncthreads();
        {
            uint4* dh = reinterpret_cast<uint4*>(&Ash[srow][skh]);
            uint4* dl = reinterpret_cast<uint4*>(&Asl[srow][skh]);
            dh[0] = make_uint4(hw[0], hw[1], hw[2], hw[3]);
            dh[1] = make_uint4(hw[4], hw[5], hw[6], hw[7]);
            dl[0] = make_uint4(lw[0], lw[1], lw[2], lw[3]);
            dl[1] = make_uint4(lw[4], lw[5], lw[6], lw[7]);
        }
        {
            const uint4* sh = reinterpret_cast<const uint4*>(Bh + bcol_base + k0);
            const uint4* sl = reinterpret_cast<const uint4*>(Bl + bcol_base + k0);
            uint4* dh = reinterpret_cast<uint4*>(&Bsh[srow][skh]);
            uint4* dl = reinterpret_cast<uint4*>(&Bsl[srow][skh]);
            dh[0] = sh[0]; dh[1] = sh[1];
            dl[0] = sl[0]; dl[1] = sl[1];
        }
        __syncthreads();

        bf16x8 ah[4], al[4], bh[4], bl[4];
#pragma unroll
        for (int i = 0; i < 4; ++i) {
            int r = wm * 64 + i * 16 + lr;
            ah[i] = *reinterpret_cast<const bf16x8*>(&Ash[r][lk]);
            al[i] = *reinterpret_cast<const bf16x8*>(&Asl[r][lk]);
        }
#pragma unroll
        for (int j = 0; j < 4; ++j) {
            int c = wn * 64 + j * 16 + lr;
            bh[j] = *reinterpret_cast<const bf16x8*>(&Bsh[c][lk]);
            bl[j] = *reinterpret_cast<const bf16x8*>(&Bsl[c][lk]);
        }
#pragma unroll
        for (int i = 0; i < 4; ++i)
#pragma unroll
            for (int j = 0; j < 4; ++j) {
                acc[i][j] = __builtin_amdgcn_mfma_f32_16x16x32_bf16(ah[i], bh[j], acc[i][j], 0, 0, 0);
                acc[i][j] = __builtin_amdgcn_mfma_f32_16x16x32_bf16(ah[i], bl[j], acc[i][j], 0, 0, 0);
                acc[i][j] = __builtin_amdgcn_mfma_f32_16x16x32_bf16(al[i], bh[j], acc[i][j], 0, 0, 0);
            }
    }

    // D mapping: col = lane&15, row = (lane>>4)*4 + reg
#pragma unroll
    for (int i = 0; i < 4; ++i) {
#pragma unroll
        for (int r = 0; r < 4; ++r) {
            int row_g = bm + wm * 64 + i * 16 + (l >> 4) * 4 + r;
            if (row_g >= M) continue;
#pragma unroll
            for (int j = 0; j < 4; ++j) {
                int col_g = bn + wn * 64 + j * 16 + lr;
                Cb[(size_t)row_g * Nc + col_g] = f2bf(acc[i][j][r]);
            }
        }
    }
}

// ---------------- attention logit precompute (bf16 h) ----------------

__global__ void compute_al_k(const unsigned short* __restrict__ h,
                             const float* __restrict__ a_src, const float* __restrict__ a_dst,
                             float* __restrict__ al_s, float* __restrict__ al_d, int n) {
    int node = blockIdx.x;
    int t = threadIdx.x;
    int hd = t >> 5, d = t & 31;
    float hv = bf2f(h[(size_t)node * 256 + t]);
    float ps = hv * a_src[t];
    float pd = hv * a_dst[t];
#pragma unroll
    for (int off = 16; off; off >>= 1) {
        ps += __shfl_xor(ps, off, 32);
        pd += __shfl_xor(pd, off, 32);
    }
    if (d == 0) {
        al_s[node * 8 + hd] = ps;
        al_d[node * 8 + hd] = pd;
    }
}

// layer 3: h [N,128] padded bf16, single head over 40 dims
__global__ void compute_al3_k(const unsigned short* __restrict__ h,
                              const float* __restrict__ a_src, const float* __restrict__ a_dst,
                              float* __restrict__ al_s, float* __restrict__ al_d, int n) {
    int wid = threadIdx.x >> 6, lane = threadIdx.x & 63;
    int node = blockIdx.x * 4 + wid;
    if (node >= n) return;
    float hv = (lane < 40) ? bf2f(h[(size_t)node * 128 + lane]) : 0.f;
    float ps = (lane < 40) ? hv * a_src[lane] : 0.f;
    float pd = (lane < 40) ? hv * a_dst[lane] : 0.f;
#pragma unroll
    for (int off = 32; off; off >>= 1) {
        ps += __shfl_xor(ps, off, 64);
        pd += __shfl_xor(pd, off, 64);
    }
    if (lane == 0) { al_s[node] = ps; al_d[node] = pd; }
}

// ---------------- softmax + aggregation: one WAVE per dst, no LDS, no barriers ----------------
// lane l owns cols 4l..4l+3 (ushort4 of bf16 h row), head hd = l>>3.
// Per-head max / weight / denom computed redundantly per lane (broadcast loads) -> no reductions.

template <bool ELU>
__global__ __launch_bounds__(256) void gat_aggregate_wave_k(const unsigned short* __restrict__ h,
                                                            const float* __restrict__ al_s,
                                                            const float* __restrict__ al_d,
                                                            const int* __restrict__ row_ptr,
                                                            const int* __restrict__ srcs,
                                                            const float* __restrict__ bias,
                                                            float* __restrict__ out, int n) {
    int wid = threadIdx.x >> 6, lane = threadIdx.x & 63;
    int dst = blockIdx.x * 4 + wid;
    if (dst >= n) return;
    int hd = lane >> 3;
    int beg = row_ptr[dst], end = row_ptr[dst + 1];   // deg >= 1 (self loop)
    float ald = al_d[dst * 8 + hd];

    // pass 1: per-head max (redundant across the 8 lanes of a head group)
    float m = -1e30f;
    for (int i = beg; i < end; ++i) {
        int s = srcs[i];
        float l = al_s[s * 8 + hd] + ald;
        l = (l > 0.f) ? l : NEG_SLOPE * l;
        m = fmaxf(m, l);
    }

    // pass 2: weighted gather-accumulate with 1-deep prefetch
    const ushort4* hp = reinterpret_cast<const ushort4*>(h);
    float4 acc = make_float4(0.f, 0.f, 0.f, 0.f);
    float sw = 0.f;
    int s0 = srcs[beg];
    float a_pre = al_s[s0 * 8 + hd];
    ushort4 v_pre = hp[(size_t)s0 * 64 + lane];
    for (int i = beg; i < end; ++i) {
        float a_cur = a_pre;
        ushort4 v = v_pre;
        if (i + 1 < end) {
            int s2 = srcs[i + 1];
            a_pre = al_s[s2 * 8 + hd];
            v_pre = hp[(size_t)s2 * 64 + lane];
        }
        float l = a_cur + ald;
        l = (l > 0.f) ? l : NEG_SLOPE * l;
        float wgt = __expf(l - m);
        sw += wgt;
        acc.x = fmaf(wgt, bf2f(v.x), acc.x);
        acc.y = fmaf(wgt, bf2f(v.y), acc.y);
        acc.z = fmaf(wgt, bf2f(v.z), acc.z);
        acc.w = fmaf(wgt, bf2f(v.w), acc.w);
    }

    float inv = 1.f / (sw + 1e-16f);
    float4 b4 = reinterpret_cast<const float4*>(bias)[lane];
    float4 o;
    o.x = acc.x * inv + b4.x;
    o.y = acc.y * inv + b4.y;
    o.z = acc.z * inv + b4.z;
    o.w = acc.w * inv + b4.w;
    if (ELU) {
        o.x = (o.x > 0.f) ? o.x : expm1f(o.x);
        o.y = (o.y > 0.f) ? o.y : expm1f(o.y);
        o.z = (o.z > 0.f) ? o.z : expm1f(o.z);
        o.w = (o.w > 0.f) ? o.w : expm1f(o.w);
    }
    reinterpret_cast<float4*>(out + (size_t)dst * 256)[lane] = o;
}

// layer 3: one wave per dst, h [N,128] padded bf16, 40 out cols, 1 head, no ELU
__global__ __launch_bounds__(256) void gat_aggregate3_wave_k(const unsigned short* __restrict__ h,
                                                             const float* __restrict__ al_s,
                                                             const float* __restrict__ al_d,
                                                             const int* __restrict__ row_ptr,
                                                             const int* __restrict__ srcs,
                                                             const float* __restrict__ bias,
                                                             float* __restrict__ out, int n) {
    int wid = threadIdx.x >> 6, lane = threadIdx.x & 63;
    int dst = blockIdx.x * 4 + wid;
    if (dst >= n) return;
    int beg = row_ptr[dst], end = row_ptr[dst + 1];
    float ald = al_d[dst];

    float m = -1e30f;
    for (int i = beg; i < end; ++i) {
        int s = srcs[i];
        float l = al_s[s] + ald;
        l = (l > 0.f) ? l : NEG_SLOPE * l;
        m = fmaxf(m, l);
    }

    float acc = 0.f, sw = 0.f;
    for (int i = beg; i < end; ++i) {
        int s = srcs[i];
        float l = al_s[s] + ald;
        l = (l > 0.f) ? l : NEG_SLOPE * l;
        float wgt = __expf(l - m);
        sw += wgt;
        if (lane < 40) acc = fmaf(wgt, bf2f(h[(size_t)s * 128 + lane]), acc);
    }
    if (lane < 40) out[(size_t)dst * 40 + lane] = acc / (sw + 1e-16f) + bias[lane];
}

// ---------------- launch ----------------

extern "C" void kernel_launch(void* const* d_in, const int* in_sizes, int n_in,
                              void* d_out, int out_size, void* d_ws, size_t ws_size,
                              hipStream_t stream) {
    const float* x   = (const float*)d_in[0];
    const int*   ei  = (const int*)d_in[1];
    const float* W1  = (const float*)d_in[2];
    const float* as1 = (const float*)d_in[3];
    const float* ad1 = (const float*)d_in[4];
    const float* b1  = (const float*)d_in[5];
    const float* W2  = (const float*)d_in[6];
    const float* as2 = (const float*)d_in[7];
    const float* ad2 = (const float*)d_in[8];
    const float* b2  = (const float*)d_in[9];
    const float* W3  = (const float*)d_in[10];
    const float* as3 = (const float*)d_in[11];
    const float* ad3 = (const float*)d_in[12];
    const float* b3  = (const float*)d_in[13];

    const int N = in_sizes[0] / 128;   // 50000
    const int E = in_sizes[1] / 2;     // 800000
    const int ET = E + N;

    char* ws = (char*)d_ws;
    size_t off = 0;
    auto alloc = [&](size_t bytes) -> void* {
        void* p = ws + off;
        off += (bytes + 255) & ~(size_t)255;
        return p;
    };
    int*   row_ptr = (int*)alloc(sizeof(int) * (N + 1));
    int*   pos     = (int*)alloc(sizeof(int) * N);
    int*   srcs    = (int*)alloc(sizeof(int) * ET);
    int*   bsums   = (int*)alloc(sizeof(int) * 64);
    float* als     = (float*)alloc(sizeof(float) * N * 8);
    float* ald     = (float*)alloc(sizeof(float) * N * 8);
    unsigned short* hb16 = (unsigned short*)alloc(sizeof(unsigned short) * (size_t)N * 256);
    float* obuf    = (float*)alloc(sizeof(float) * (size_t)N * 256);
    unsigned short* wbh = (unsigned short*)alloc(sizeof(unsigned short) * 256 * 256);
    unsigned short* wbl = (unsigned short*)alloc(sizeof(unsigned short) * 256 * 256);
    (void)ws_size;

    const int nb = (N + 1023) / 1024;

    // --- CSR build ---
    hipMemsetAsync(pos, 0, sizeof(int) * N, stream);
    count_edges_k<<<(ET + 255) / 256, 256, 0, stream>>>(ei, E, N, pos);
    scan1_k<<<nb, 256, 0, stream>>>(pos, row_ptr, bsums, N);
    scan2_k<<<1, 64, 0, stream>>>(bsums, nb);
    scan3_k<<<(N + 1 + 255) / 256, 256, 0, stream>>>(row_ptr, pos, bsums, N, ET);
    scatter_edges_k<<<(ET + 255) / 256, 256, 0, stream>>>(ei, E, N, pos, srcs);

    const int gy = (N + 127) / 128;
    const int gagg = (N + 3) / 4;

    // --- layer 1: x[N,128] @ W1[128,256] (MFMA split-bf16 -> bf16 h) ---
    convert_w_k<<<(128 * 256 + 255) / 256, 256, 0, stream>>>(W1, wbh, wbl, 128, 256);
    mfma_gemm_k<<<dim3(2, gy), 256, 0, stream>>>(x, wbh, wbl, hb16, N, 128, 256);
    compute_al_k<<<N, 256, 0, stream>>>(hb16, as1, ad1, als, ald, N);
    gat_aggregate_wave_k<true><<<gagg, 256, 0, stream>>>(hb16, als, ald, row_ptr, srcs, b1, obuf, N);

    // --- layer 2: obuf[N,256] @ W2[256,256] ---
    convert_w_k<<<(256 * 256 + 255) / 256, 256, 0, stream>>>(W2, wbh, wbl, 256, 256);
    mfma_gemm_k<<<dim3(2, gy), 256, 0, stream>>>(obuf, wbh, wbl, hb16, N, 256, 256);
    compute_al_k<<<N, 256, 0, stream>>>(hb16, as2, ad2, als, ald, N);
    gat_aggregate_wave_k<true><<<gagg, 256, 0, stream>>>(hb16, als, ald, row_ptr, srcs, b2, obuf, N);

    // --- layer 3: obuf[N,256] @ W3[256,40] via MFMA (cols padded to 128) -> h3 [N,128] bf16 ---
    hipMemsetAsync(wbh, 0, sizeof(unsigned short) * 128 * 256, stream);
    hipMemsetAsync(wbl, 0, sizeof(unsigned short) * 128 * 256, stream);
    convert_w3_k<<<(256 * 40 + 255) / 256, 256, 0, stream>>>(W3, wbh, wbl, 256, 40);
    mfma_gemm_k<<<dim3(1, gy), 256, 0, stream>>>(obuf, wbh, wbl, hb16, N, 256, 128);
    compute_al3_k<<<gagg, 256, 0, stream>>>(hb16, as3, ad3, als, ald, N);
    gat_aggregate3_wave_k<<<gagg, 256, 0, stream>>>(hb16, als, ald, row_ptr, srcs, b3, (float*)d_out, N);
}

// Round 6
// 492.674 us; speedup vs baseline: 1.3961x; 1.3961x over previous
//
#include <hip/hip_runtime.h>
#include <hip/hip_bf16.h>

#define NEG_SLOPE 0.2f

typedef __attribute__((ext_vector_type(8))) short bf16x8;
typedef __attribute__((ext_vector_type(4))) float f32x4;

__device__ __forceinline__ unsigned short f2bf(float v) {
    union { float f; unsigned int u; } x; x.f = v;
    unsigned int r = x.u + 0x7fffu + ((x.u >> 16) & 1u);
    return (unsigned short)(r >> 16);
}
__device__ __forceinline__ float bf2f(unsigned short b) {
    union { unsigned int u; float f; } x; x.u = ((unsigned int)b) << 16;
    return x.f;
}

// ---------------- CSR build ----------------

__global__ void count_edges_k(const int* __restrict__ ei, int E, int n, int* __restrict__ cnt) {
    int e = blockIdx.x * 256 + threadIdx.x;
    int ET = E + n;
    if (e >= ET) return;
    int d = (e < E) ? ei[E + e] : (e - E);
    atomicAdd(&cnt[d], 1);
}

__global__ void scan1_k(const int* __restrict__ cnt, int* __restrict__ row_ptr,
                        int* __restrict__ bsums, int n) {
    __shared__ int sd[256];
    int b = blockIdx.x, t = threadIdx.x;
    int base = b * 1024 + t * 4;
    int v[4];
    int loc = 0;
#pragma unroll
    for (int j = 0; j < 4; ++j) {
        v[j] = (base + j < n) ? cnt[base + j] : 0;
        loc += v[j];
    }
    sd[t] = loc;
    __syncthreads();
    for (int off = 1; off < 256; off <<= 1) {
        int x = (t >= off) ? sd[t - off] : 0;
        __syncthreads();
        sd[t] += x;
        __syncthreads();
    }
    int run = sd[t] - loc;
    if (t == 255) bsums[b] = sd[t];
#pragma unroll
    for (int j = 0; j < 4; ++j) {
        if (base + j < n) row_ptr[base + j] = run;
        run += v[j];
    }
}

__global__ void scan2_k(int* __restrict__ bsums, int nb) {
    if (threadIdx.x == 0 && blockIdx.x == 0) {
        int run = 0;
        for (int i = 0; i < nb; ++i) { int x = bsums[i]; bsums[i] = run; run += x; }
    }
}

__global__ void scan3_k(int* __restrict__ row_ptr, int* __restrict__ pos,
                        const int* __restrict__ bsums, int n, int total) {
    int idx = blockIdx.x * 256 + threadIdx.x;
    if (idx < n) {
        int vv = row_ptr[idx] + bsums[idx >> 10];
        row_ptr[idx] = vv;
        pos[idx] = vv;
    } else if (idx == n) {
        row_ptr[n] = total;
    }
}

__global__ void scatter_edges_k(const int* __restrict__ ei, int E, int n,
                                int* __restrict__ pos, int* __restrict__ srcs) {
    int e = blockIdx.x * 256 + threadIdx.x;
    int ET = E + n;
    if (e >= ET) return;
    int s, d;
    if (e < E) { s = ei[e]; d = ei[E + e]; }
    else       { s = e - E; d = e - E; }
    int idx = atomicAdd(&pos[d], 1);
    srcs[idx] = s;
}

// ---------------- weight pre-convert ----------------

__global__ void convert_w_k(const float* __restrict__ W,
                            unsigned short* __restrict__ Bh, unsigned short* __restrict__ Bl,
                            int K, int Nc) {
    int idx = blockIdx.x * 256 + threadIdx.x;
    if (idx >= K * Nc) return;
    int k = idx / Nc, c = idx - k * Nc;
    float v = W[idx];
    unsigned short h = f2bf(v);
    float r = v - bf2f(h);
    Bh[c * K + k] = h;
    Bl[c * K + k] = f2bf(r);
}

// ---------------- split-bf16 MFMA GEMM -> bf16 output ----------------

#define GPAD 40

__global__ __launch_bounds__(256) void mfma_gemm_k(const float* __restrict__ A,
                                                   const unsigned short* __restrict__ Bh,
                                                   const unsigned short* __restrict__ Bl,
                                                   unsigned short* __restrict__ Cb,
                                                   int M, int K, int Nc) {
    __shared__ unsigned short Ash[128][GPAD];
    __shared__ unsigned short Asl[128][GPAD];
    __shared__ unsigned short Bsh[128][GPAD];
    __shared__ unsigned short Bsl[128][GPAD];

    int bm = blockIdx.y * 128;
    int bn = blockIdx.x * 128;
    int t = threadIdx.x;
    int w = t >> 6, l = t & 63;
    int wm = w >> 1, wn = w & 1;
    int lr = l & 15, lk = (l >> 4) * 8;

    int srow = t >> 1;
    int skh  = (t & 1) * 16;

    f32x4 acc[4][4];
#pragma unroll
    for (int i = 0; i < 4; ++i)
#pragma unroll
        for (int j = 0; j < 4; ++j)
            acc[i][j] = (f32x4){0.f, 0.f, 0.f, 0.f};

    const int arow = bm + srow;
    const bool arow_ok = (arow < M);
    const size_t acol_base = (size_t)arow * K + skh;
    const size_t bcol_base = (size_t)(bn + srow) * K + skh;

    for (int k0 = 0; k0 < K; k0 += 32) {
        float vv[16];
        if (arow_ok) {
            const float4* ap = reinterpret_cast<const float4*>(A + acol_base + k0);
#pragma unroll
            for (int q = 0; q < 4; ++q) {
                float4 v4 = ap[q];
                vv[4 * q + 0] = v4.x; vv[4 * q + 1] = v4.y;
                vv[4 * q + 2] = v4.z; vv[4 * q + 3] = v4.w;
            }
        } else {
#pragma unroll
            for (int q = 0; q < 16; ++q) vv[q] = 0.f;
        }
        unsigned int hw[8], lw[8];
#pragma unroll
        for (int q = 0; q < 8; ++q) {
            unsigned short h0 = f2bf(vv[2 * q]);
            unsigned short h1 = f2bf(vv[2 * q + 1]);
            unsigned short l0 = f2bf(vv[2 * q] - bf2f(h0));
            unsigned short l1 = f2bf(vv[2 * q + 1] - bf2f(h1));
            hw[q] = (unsigned int)h0 | ((unsigned int)h1 << 16);
            lw[q] = (unsigned int)l0 | ((unsigned int)l1 << 16);
        }
        __syncthreads();
        {
            uint4* dh = reinterpret_cast<uint4*>(&Ash[srow][skh]);
            uint4* dl = reinterpret_cast<uint4*>(&Asl[srow][skh]);
            dh[0] = make_uint4(hw[0], hw[1], hw[2], hw[3]);
            dh[1] = make_uint4(hw[4], hw[5], hw[6], hw[7]);
            dl[0] = make_uint4(lw[0], lw[1], lw[2], lw[3]);
            dl[1] = make_uint4(lw[4], lw[5], lw[6], lw[7]);
        }
        {
            const uint4* sh = reinterpret_cast<const uint4*>(Bh + bcol_base + k0);
            const uint4* sl = reinterpret_cast<const uint4*>(Bl + bcol_base + k0);
            uint4* dh = reinterpret_cast<uint4*>(&Bsh[srow][skh]);
            uint4* dl = reinterpret_cast<uint4*>(&Bsl[srow][skh]);
            dh[0] = sh[0]; dh[1] = sh[1];
            dl[0] = sl[0]; dl[1] = sl[1];
        }
        __syncthreads();

        bf16x8 ah[4], al[4], bh[4], bl[4];
#pragma unroll
        for (int i = 0; i < 4; ++i) {
            int r = wm * 64 + i * 16 + lr;
            ah[i] = *reinterpret_cast<const bf16x8*>(&Ash[r][lk]);
            al[i] = *reinterpret_cast<const bf16x8*>(&Asl[r][lk]);
        }
#pragma unroll
        for (int j = 0; j < 4; ++j) {
            int c = wn * 64 + j * 16 + lr;
            bh[j] = *reinterpret_cast<const bf16x8*>(&Bsh[c][lk]);
            bl[j] = *reinterpret_cast<const bf16x8*>(&Bsl[c][lk]);
        }
#pragma unroll
        for (int i = 0; i < 4; ++i)
#pragma unroll
            for (int j = 0; j < 4; ++j) {
                acc[i][j] = __builtin_amdgcn_mfma_f32_16x16x32_bf16(ah[i], bh[j], acc[i][j], 0, 0, 0);
                acc[i][j] = __builtin_amdgcn_mfma_f32_16x16x32_bf16(ah[i], bl[j], acc[i][j], 0, 0, 0);
                acc[i][j] = __builtin_amdgcn_mfma_f32_16x16x32_bf16(al[i], bh[j], acc[i][j], 0, 0, 0);
            }
    }

#pragma unroll
    for (int i = 0; i < 4; ++i) {
#pragma unroll
        for (int r = 0; r < 4; ++r) {
            int row_g = bm + wm * 64 + i * 16 + (l >> 4) * 4 + r;
            if (row_g >= M) continue;
#pragma unroll
            for (int j = 0; j < 4; ++j) {
                int col_g = bn + wn * 64 + j * 16 + lr;
                Cb[(size_t)row_g * Nc + col_g] = f2bf(acc[i][j][r]);
            }
        }
    }
}

// ---------------- attention logit precompute (bf16 h) ----------------

__global__ void compute_al_k(const unsigned short* __restrict__ h,
                             const float* __restrict__ a_src, const float* __restrict__ a_dst,
                             float* __restrict__ al_s, float* __restrict__ al_d, int n) {
    int node = blockIdx.x;
    int t = threadIdx.x;
    int hd = t >> 5, d = t & 31;
    float hv = bf2f(h[(size_t)node * 256 + t]);
    float ps = hv * a_src[t];
    float pd = hv * a_dst[t];
#pragma unroll
    for (int off = 16; off; off >>= 1) {
        ps += __shfl_xor(ps, off, 32);
        pd += __shfl_xor(pd, off, 32);
    }
    if (d == 0) {
        al_s[node * 8 + hd] = ps;
        al_d[node * 8 + hd] = pd;
    }
}

// layer 3: h [N,128] padded bf16, single head over 40 dims
__global__ void compute_al3_k(const unsigned short* __restrict__ h,
                              const float* __restrict__ a_src, const float* __restrict__ a_dst,
                              float* __restrict__ al_s, float* __restrict__ al_d, int n) {
    int wid = threadIdx.x >> 6, lane = threadIdx.x & 63;
    int node = blockIdx.x * 4 + wid;
    if (node >= n) return;
    float hv = (lane < 40) ? bf2f(h[(size_t)node * 128 + lane]) : 0.f;
    float ps = (lane < 40) ? hv * a_src[lane] : 0.f;
    float pd = (lane < 40) ? hv * a_dst[lane] : 0.f;
#pragma unroll
    for (int off = 32; off; off >>= 1) {
        ps += __shfl_xor(ps, off, 64);
        pd += __shfl_xor(pd, off, 64);
    }
    if (lane == 0) { al_s[node] = ps; al_d[node] = pd; }
}

// ---------------- edge softmax: one THREAD per (dst, head) ----------------
// writes w[i*8+hd] (exp weight) and inv[dst*8+hd] (1/denominator)

__global__ __launch_bounds__(256) void edge_softmax_k(const float* __restrict__ al_s,
                                                      const float* __restrict__ al_d,
                                                      const int* __restrict__ row_ptr,
                                                      const int* __restrict__ srcs,
                                                      float* __restrict__ w,
                                                      float* __restrict__ inv, int n8) {
    int tid = blockIdx.x * 256 + threadIdx.x;
    if (tid >= n8) return;
    int dst = tid >> 3, hd = tid & 7;
    int beg = row_ptr[dst], end = row_ptr[dst + 1];
    float ald = al_d[tid];

    float m = -1e30f;
    int i = beg;
    for (; i + 2 <= end; i += 2) {
        int s0 = srcs[i], s1 = srcs[i + 1];
        float l0 = al_s[s0 * 8 + hd] + ald;
        float l1 = al_s[s1 * 8 + hd] + ald;
        l0 = (l0 > 0.f) ? l0 : NEG_SLOPE * l0;
        l1 = (l1 > 0.f) ? l1 : NEG_SLOPE * l1;
        m = fmaxf(m, fmaxf(l0, l1));
    }
    if (i < end) {
        int s0 = srcs[i];
        float l0 = al_s[s0 * 8 + hd] + ald;
        l0 = (l0 > 0.f) ? l0 : NEG_SLOPE * l0;
        m = fmaxf(m, l0);
    }

    float sw = 0.f;
    for (i = beg; i < end; ++i) {
        int s = srcs[i];
        float l = al_s[s * 8 + hd] + ald;
        l = (l > 0.f) ? l : NEG_SLOPE * l;
        float e = __expf(l - m);
        w[(size_t)i * 8 + hd] = e;
        sw += e;
    }
    inv[tid] = 1.f / (sw + 1e-16f);
}

// layer 3: one thread per dst, single head
__global__ __launch_bounds__(256) void edge_softmax3_k(const float* __restrict__ al_s,
                                                       const float* __restrict__ al_d,
                                                       const int* __restrict__ row_ptr,
                                                       const int* __restrict__ srcs,
                                                       float* __restrict__ w,
                                                       float* __restrict__ inv, int n) {
    int dst = blockIdx.x * 256 + threadIdx.x;
    if (dst >= n) return;
    int beg = row_ptr[dst], end = row_ptr[dst + 1];
    float ald = al_d[dst];

    float m = -1e30f;
    int i = beg;
    for (; i + 2 <= end; i += 2) {
        int s0 = srcs[i], s1 = srcs[i + 1];
        float l0 = al_s[s0] + ald;
        float l1 = al_s[s1] + ald;
        l0 = (l0 > 0.f) ? l0 : NEG_SLOPE * l0;
        l1 = (l1 > 0.f) ? l1 : NEG_SLOPE * l1;
        m = fmaxf(m, fmaxf(l0, l1));
    }
    if (i < end) {
        int s0 = srcs[i];
        float l0 = al_s[s0] + ald;
        l0 = (l0 > 0.f) ? l0 : NEG_SLOPE * l0;
        m = fmaxf(m, l0);
    }

    float sw = 0.f;
    for (i = beg; i < end; ++i) {
        int s = srcs[i];
        float l = al_s[s] + ald;
        l = (l > 0.f) ? l : NEG_SLOPE * l;
        float e = __expf(l - m);
        w[i] = e;
        sw += e;
    }
    inv[dst] = 1.f / (sw + 1e-16f);
}

// ---------------- pure gather-FMA aggregation: one WAVE per dst ----------------
// lane owns cols 4l..4l+3 (ushort4 of bf16 h row), head hd = l>>3; weights precomputed.

template <bool ELU>
__global__ __launch_bounds__(256) void gat_gather_k(const unsigned short* __restrict__ h,
                                                    const float* __restrict__ w,
                                                    const float* __restrict__ inv,
                                                    const int* __restrict__ row_ptr,
                                                    const int* __restrict__ srcs,
                                                    const float* __restrict__ bias,
                                                    float* __restrict__ out, int n) {
    int wid = threadIdx.x >> 6, lane = threadIdx.x & 63;
    int dst = blockIdx.x * 4 + wid;
    if (dst >= n) return;
    int hd = lane >> 3;
    int beg = row_ptr[dst], end = row_ptr[dst + 1];
    const ushort4* hp = reinterpret_cast<const ushort4*>(h);

    float4 acc = make_float4(0.f, 0.f, 0.f, 0.f);
    int i = beg;
    for (; i + 4 <= end; i += 4) {
        int s0 = srcs[i + 0], s1 = srcs[i + 1], s2 = srcs[i + 2], s3 = srcs[i + 3];
        float w0 = w[(size_t)(i + 0) * 8 + hd];
        float w1 = w[(size_t)(i + 1) * 8 + hd];
        float w2 = w[(size_t)(i + 2) * 8 + hd];
        float w3 = w[(size_t)(i + 3) * 8 + hd];
        ushort4 v0 = hp[(size_t)s0 * 64 + lane];
        ushort4 v1 = hp[(size_t)s1 * 64 + lane];
        ushort4 v2 = hp[(size_t)s2 * 64 + lane];
        ushort4 v3 = hp[(size_t)s3 * 64 + lane];
        acc.x = fmaf(w0, bf2f(v0.x), acc.x);
        acc.y = fmaf(w0, bf2f(v0.y), acc.y);
        acc.z = fmaf(w0, bf2f(v0.z), acc.z);
        acc.w = fmaf(w0, bf2f(v0.w), acc.w);
        acc.x = fmaf(w1, bf2f(v1.x), acc.x);
        acc.y = fmaf(w1, bf2f(v1.y), acc.y);
        acc.z = fmaf(w1, bf2f(v1.z), acc.z);
        acc.w = fmaf(w1, bf2f(v1.w), acc.w);
        acc.x = fmaf(w2, bf2f(v2.x), acc.x);
        acc.y = fmaf(w2, bf2f(v2.y), acc.y);
        acc.z = fmaf(w2, bf2f(v2.z), acc.z);
        acc.w = fmaf(w2, bf2f(v2.w), acc.w);
        acc.x = fmaf(w3, bf2f(v3.x), acc.x);
        acc.y = fmaf(w3, bf2f(v3.y), acc.y);
        acc.z = fmaf(w3, bf2f(v3.z), acc.z);
        acc.w = fmaf(w3, bf2f(v3.w), acc.w);
    }
    for (; i < end; ++i) {
        int s = srcs[i];
        float wgt = w[(size_t)i * 8 + hd];
        ushort4 v = hp[(size_t)s * 64 + lane];
        acc.x = fmaf(wgt, bf2f(v.x), acc.x);
        acc.y = fmaf(wgt, bf2f(v.y), acc.y);
        acc.z = fmaf(wgt, bf2f(v.z), acc.z);
        acc.w = fmaf(wgt, bf2f(v.w), acc.w);
    }

    float iv = inv[dst * 8 + hd];
    float4 b4 = reinterpret_cast<const float4*>(bias)[lane];
    float4 o;
    o.x = acc.x * iv + b4.x;
    o.y = acc.y * iv + b4.y;
    o.z = acc.z * iv + b4.z;
    o.w = acc.w * iv + b4.w;
    if (ELU) {
        o.x = (o.x > 0.f) ? o.x : expm1f(o.x);
        o.y = (o.y > 0.f) ? o.y : expm1f(o.y);
        o.z = (o.z > 0.f) ? o.z : expm1f(o.z);
        o.w = (o.w > 0.f) ? o.w : expm1f(o.w);
    }
    reinterpret_cast<float4*>(out + (size_t)dst * 256)[lane] = o;
}

// layer 3: wave per dst, 4 edges in parallel (16 lanes x ushort4 each), h [N,128] padded
__global__ __launch_bounds__(256) void gat_gather3_k(const unsigned short* __restrict__ h,
                                                     const float* __restrict__ w,
                                                     const float* __restrict__ inv,
                                                     const int* __restrict__ row_ptr,
                                                     const int* __restrict__ srcs,
                                                     const float* __restrict__ bias,
                                                     float* __restrict__ out, int n) {
    int wid = threadIdx.x >> 6, lane = threadIdx.x & 63;
    int dst = blockIdx.x * 4 + wid;
    if (dst >= n) return;
    int es = lane >> 4, cl = lane & 15;
    int beg = row_ptr[dst], end = row_ptr[dst + 1];

    float4 acc = make_float4(0.f, 0.f, 0.f, 0.f);
    for (int i = beg; i < end; i += 4) {
        int idx = i + es;
        bool ok = (idx < end);
        int s = ok ? srcs[idx] : srcs[beg];
        float wgt = ok ? w[idx] : 0.f;
        ushort4 v = reinterpret_cast<const ushort4*>(h + (size_t)s * 128)[cl];
        acc.x = fmaf(wgt, bf2f(v.x), acc.x);
        acc.y = fmaf(wgt, bf2f(v.y), acc.y);
        acc.z = fmaf(wgt, bf2f(v.z), acc.z);
        acc.w = fmaf(wgt, bf2f(v.w), acc.w);
    }
#pragma unroll
    for (int off = 16; off <= 32; off <<= 1) {
        acc.x += __shfl_xor(acc.x, off, 64);
        acc.y += __shfl_xor(acc.y, off, 64);
        acc.z += __shfl_xor(acc.z, off, 64);
        acc.w += __shfl_xor(acc.w, off, 64);
    }
    if (es == 0 && cl < 10) {
        float iv = inv[dst];
        int c = cl * 4;
        float4 b4 = *reinterpret_cast<const float4*>(bias + c);
        float4 o;
        o.x = acc.x * iv + b4.x;
        o.y = acc.y * iv + b4.y;
        o.z = acc.z * iv + b4.z;
        o.w = acc.w * iv + b4.w;
        *reinterpret_cast<float4*>(out + (size_t)dst * 40 + c) = o;
    }
}

// ---------------- launch ----------------

extern "C" void kernel_launch(void* const* d_in, const int* in_sizes, int n_in,
                              void* d_out, int out_size, void* d_ws, size_t ws_size,
                              hipStream_t stream) {
    const float* x   = (const float*)d_in[0];
    const int*   ei  = (const int*)d_in[1];
    const float* W1  = (const float*)d_in[2];
    const float* as1 = (const float*)d_in[3];
    const float* ad1 = (const float*)d_in[4];
    const float* b1  = (const float*)d_in[5];
    const float* W2  = (const float*)d_in[6];
    const float* as2 = (const float*)d_in[7];
    const float* ad2 = (const float*)d_in[8];
    const float* b2  = (const float*)d_in[9];
    const float* W3  = (const float*)d_in[10];
    const float* as3 = (const float*)d_in[11];
    const float* ad3 = (const float*)d_in[12];
    const float* b3  = (const float*)d_in[13];

    const int N = in_sizes[0] / 128;   // 50000
    const int E = in_sizes[1] / 2;     // 800000
    const int ET = E + N;

    char* ws = (char*)d_ws;
    size_t off = 0;
    auto alloc = [&](size_t bytes) -> void* {
        void* p = ws + off;
        off += (bytes + 255) & ~(size_t)255;
        return p;
    };
    int*   row_ptr = (int*)alloc(sizeof(int) * (N + 1));
    int*   pos     = (int*)alloc(sizeof(int) * N);
    int*   srcs    = (int*)alloc(sizeof(int) * ET);
    int*   bsums   = (int*)alloc(sizeof(int) * 64);
    float* als     = (float*)alloc(sizeof(float) * N * 8);
    float* ald     = (float*)alloc(sizeof(float) * N * 8);
    float* wbuf    = (float*)alloc(sizeof(float) * (size_t)ET * 8);   // edge weights (reused by L3)
    float* invb    = (float*)alloc(sizeof(float) * N * 8);            // 1/denominator (reused by L3)
    unsigned short* hb16 = (unsigned short*)alloc(sizeof(unsigned short) * (size_t)N * 256);
    float* obuf    = (float*)alloc(sizeof(float) * (size_t)N * 256);
    unsigned short* wbh = (unsigned short*)alloc(sizeof(unsigned short) * 256 * 256);
    unsigned short* wbl = (unsigned short*)alloc(sizeof(unsigned short) * 256 * 256);
    (void)ws_size;

    const int nb = (N + 1023) / 1024;

    // --- CSR build ---
    hipMemsetAsync(pos, 0, sizeof(int) * N, stream);
    count_edges_k<<<(ET + 255) / 256, 256, 0, stream>>>(ei, E, N, pos);
    scan1_k<<<nb, 256, 0, stream>>>(pos, row_ptr, bsums, N);
    scan2_k<<<1, 64, 0, stream>>>(bsums, nb);
    scan3_k<<<(N + 1 + 255) / 256, 256, 0, stream>>>(row_ptr, pos, bsums, N, ET);
    scatter_edges_k<<<(ET + 255) / 256, 256, 0, stream>>>(ei, E, N, pos, srcs);

    const int gy = (N + 127) / 128;
    const int gagg = (N + 3) / 4;
    const int gsm = (N * 8 + 255) / 256;

    // --- layer 1: x[N,128] @ W1[128,256] (MFMA split-bf16 -> bf16 h) ---
    convert_w_k<<<(128 * 256 + 255) / 256, 256, 0, stream>>>(W1, wbh, wbl, 128, 256);
    mfma_gemm_k<<<dim3(2, gy), 256, 0, stream>>>(x, wbh, wbl, hb16, N, 128, 256);
    compute_al_k<<<N, 256, 0, stream>>>(hb16, as1, ad1, als, ald, N);
    edge_softmax_k<<<gsm, 256, 0, stream>>>(als, ald, row_ptr, srcs, wbuf, invb, N * 8);
    gat_gather_k<true><<<gagg, 256, 0, stream>>>(hb16, wbuf, invb, row_ptr, srcs, b1, obuf, N);

    // --- layer 2: obuf[N,256] @ W2[256,256] ---
    convert_w_k<<<(256 * 256 + 255) / 256, 256, 0, stream>>>(W2, wbh, wbl, 256, 256);
    mfma_gemm_k<<<dim3(2, gy), 256, 0, stream>>>(obuf, wbh, wbl, hb16, N, 256, 256);
    compute_al_k<<<N, 256, 0, stream>>>(hb16, as2, ad2, als, ald, N);
    edge_softmax_k<<<gsm, 256, 0, stream>>>(als, ald, row_ptr, srcs, wbuf, invb, N * 8);
    gat_gather_k<true><<<gagg, 256, 0, stream>>>(hb16, wbuf, invb, row_ptr, srcs, b2, obuf, N);

    // --- layer 3: obuf[N,256] @ W3[256,40] via MFMA (cols padded to 128) -> h3 [N,128] bf16 ---
    hipMemsetAsync(wbh, 0, sizeof(unsigned short) * 128 * 256, stream);
    hipMemsetAsync(wbl, 0, sizeof(unsigned short) * 128 * 256, stream);
    convert_w_k<<<(256 * 40 + 255) / 256, 256, 0, stream>>>(W3, wbh, wbl, 256, 40);
    mfma_gemm_k<<<dim3(1, gy), 256, 0, stream>>>(obuf, wbh, wbl, hb16, N, 256, 128);
    compute_al3_k<<<gagg, 256, 0, stream>>>(hb16, as3, ad3, als, ald, N);
    edge_softmax3_k<<<(N + 255) / 256, 256, 0, stream>>>(als, ald, row_ptr, srcs, wbuf, invb, N);
    gat_gather3_k<<<gagg, 256, 0, stream>>>(hb16, wbuf, invb, row_ptr, srcs, b3, (float*)d_out, N);
}

// Round 7
// 444.119 us; speedup vs baseline: 1.5487x; 1.1093x over previous
//
#include <hip/hip_runtime.h>
#include <hip/hip_bf16.h>

#define NEG_SLOPE 0.2f

typedef __attribute__((ext_vector_type(8))) short bf16x8;
typedef __attribute__((ext_vector_type(4))) float f32x4;

__device__ __forceinline__ unsigned short f2bf(float v) {
    union { float f; unsigned int u; } x; x.f = v;
    unsigned int r = x.u + 0x7fffu + ((x.u >> 16) & 1u);
    return (unsigned short)(r >> 16);
}
__device__ __forceinline__ float bf2f(unsigned short b) {
    union { unsigned int u; float f; } x; x.u = ((unsigned int)b) << 16;
    return x.f;
}

// ---------------- CSR build ----------------

__global__ void count_edges_k(const int* __restrict__ ei, int E, int n, int* __restrict__ cnt) {
    int e = blockIdx.x * 256 + threadIdx.x;
    int ET = E + n;
    if (e >= ET) return;
    int d = (e < E) ? ei[E + e] : (e - E);
    atomicAdd(&cnt[d], 1);
}

__global__ void scan1_k(const int* __restrict__ cnt, int* __restrict__ row_ptr,
                        int* __restrict__ bsums, int n) {
    __shared__ int sd[256];
    int b = blockIdx.x, t = threadIdx.x;
    int base = b * 1024 + t * 4;
    int v[4];
    int loc = 0;
#pragma unroll
    for (int j = 0; j < 4; ++j) {
        v[j] = (base + j < n) ? cnt[base + j] : 0;
        loc += v[j];
    }
    sd[t] = loc;
    __syncthreads();
    for (int off = 1; off < 256; off <<= 1) {
        int x = (t >= off) ? sd[t - off] : 0;
        __syncthreads();
        sd[t] += x;
        __syncthreads();
    }
    int run = sd[t] - loc;
    if (t == 255) bsums[b] = sd[t];
#pragma unroll
    for (int j = 0; j < 4; ++j) {
        if (base + j < n) row_ptr[base + j] = run;
        run += v[j];
    }
}

__global__ void scan2_k(int* __restrict__ bsums, int nb) {
    if (threadIdx.x == 0 && blockIdx.x == 0) {
        int run = 0;
        for (int i = 0; i < nb; ++i) { int x = bsums[i]; bsums[i] = run; run += x; }
    }
}

__global__ void scan3_k(int* __restrict__ row_ptr, int* __restrict__ pos,
                        const int* __restrict__ bsums, int n, int total) {
    int idx = blockIdx.x * 256 + threadIdx.x;
    if (idx < n) {
        int vv = row_ptr[idx] + bsums[idx >> 10];
        row_ptr[idx] = vv;
        pos[idx] = vv;
    } else if (idx == n) {
        row_ptr[n] = total;
    }
}

__global__ void scatter_edges_k(const int* __restrict__ ei, int E, int n,
                                int* __restrict__ pos, int* __restrict__ srcs) {
    int e = blockIdx.x * 256 + threadIdx.x;
    int ET = E + n;
    if (e >= ET) return;
    int s, d;
    if (e < E) { s = ei[e]; d = ei[E + e]; }
    else       { s = e - E; d = e - E; }
    int idx = atomicAdd(&pos[d], 1);
    srcs[idx] = s;
}

// ---------------- weight pre-convert: W[K][Nc] fp32 -> col-major hi/lo bf16 [Nc][K] ----------------

__global__ void convert_w_k(const float* __restrict__ W,
                            unsigned short* __restrict__ Bh, unsigned short* __restrict__ Bl,
                            int K, int Nc) {
    int idx = blockIdx.x * 256 + threadIdx.x;
    if (idx >= K * Nc) return;
    int k = idx / Nc, c = idx - k * Nc;
    float v = W[idx];
    unsigned short h = f2bf(v);
    float r = v - bf2f(h);
    Bh[c * K + k] = h;
    Bl[c * K + k] = f2bf(r);
}

// ---------------- layer-1 GEMM: fp32 A split on the fly (3 products) ----------------

#define GPAD 40

__global__ __launch_bounds__(256) void mfma_gemm_k(const float* __restrict__ A,
                                                   const unsigned short* __restrict__ Bh,
                                                   const unsigned short* __restrict__ Bl,
                                                   unsigned short* __restrict__ Cb,
                                                   int M, int K, int Nc) {
    __shared__ unsigned short Ash[128][GPAD];
    __shared__ unsigned short Asl[128][GPAD];
    __shared__ unsigned short Bsh[128][GPAD];
    __shared__ unsigned short Bsl[128][GPAD];

    int bm = blockIdx.y * 128;
    int bn = blockIdx.x * 128;
    int t = threadIdx.x;
    int w = t >> 6, l = t & 63;
    int wm = w >> 1, wn = w & 1;
    int lr = l & 15, lk = (l >> 4) * 8;

    int srow = t >> 1;
    int skh  = (t & 1) * 16;

    f32x4 acc[4][4];
#pragma unroll
    for (int i = 0; i < 4; ++i)
#pragma unroll
        for (int j = 0; j < 4; ++j)
            acc[i][j] = (f32x4){0.f, 0.f, 0.f, 0.f};

    const int arow = bm + srow;
    const bool arow_ok = (arow < M);
    const size_t acol_base = (size_t)arow * K + skh;
    const size_t bcol_base = (size_t)(bn + srow) * K + skh;

    for (int k0 = 0; k0 < K; k0 += 32) {
        float vv[16];
        if (arow_ok) {
            const float4* ap = reinterpret_cast<const float4*>(A + acol_base + k0);
#pragma unroll
            for (int q = 0; q < 4; ++q) {
                float4 v4 = ap[q];
                vv[4 * q + 0] = v4.x; vv[4 * q + 1] = v4.y;
                vv[4 * q + 2] = v4.z; vv[4 * q + 3] = v4.w;
            }
        } else {
#pragma unroll
            for (int q = 0; q < 16; ++q) vv[q] = 0.f;
        }
        unsigned int hw[8], lw[8];
#pragma unroll
        for (int q = 0; q < 8; ++q) {
            unsigned short h0 = f2bf(vv[2 * q]);
            unsigned short h1 = f2bf(vv[2 * q + 1]);
            unsigned short l0 = f2bf(vv[2 * q] - bf2f(h0));
            unsigned short l1 = f2bf(vv[2 * q + 1] - bf2f(h1));
            hw[q] = (unsigned int)h0 | ((unsigned int)h1 << 16);
            lw[q] = (unsigned int)l0 | ((unsigned int)l1 << 16);
        }
        __syncthreads();
        {
            uint4* dh = reinterpret_cast<uint4*>(&Ash[srow][skh]);
            uint4* dl = reinterpret_cast<uint4*>(&Asl[srow][skh]);
            dh[0] = make_uint4(hw[0], hw[1], hw[2], hw[3]);
            dh[1] = make_uint4(hw[4], hw[5], hw[6], hw[7]);
            dl[0] = make_uint4(lw[0], lw[1], lw[2], lw[3]);
            dl[1] = make_uint4(lw[4], lw[5], lw[6], lw[7]);
        }
        {
            const uint4* sh = reinterpret_cast<const uint4*>(Bh + bcol_base + k0);
            const uint4* sl = reinterpret_cast<const uint4*>(Bl + bcol_base + k0);
            uint4* dh = reinterpret_cast<uint4*>(&Bsh[srow][skh]);
            uint4* dl = reinterpret_cast<uint4*>(&Bsl[srow][skh]);
            dh[0] = sh[0]; dh[1] = sh[1];
            dl[0] = sl[0]; dl[1] = sl[1];
        }
        __syncthreads();

        bf16x8 ah[4], al[4], bh[4], bl[4];
#pragma unroll
        for (int i = 0; i < 4; ++i) {
            int r = wm * 64 + i * 16 + lr;
            ah[i] = *reinterpret_cast<const bf16x8*>(&Ash[r][lk]);
            al[i] = *reinterpret_cast<const bf16x8*>(&Asl[r][lk]);
        }
#pragma unroll
        for (int j = 0; j < 4; ++j) {
            int c = wn * 64 + j * 16 + lr;
            bh[j] = *reinterpret_cast<const bf16x8*>(&Bsh[c][lk]);
            bl[j] = *reinterpret_cast<const bf16x8*>(&Bsl[c][lk]);
        }
#pragma unroll
        for (int i = 0; i < 4; ++i)
#pragma unroll
            for (int j = 0; j < 4; ++j) {
                acc[i][j] = __builtin_amdgcn_mfma_f32_16x16x32_bf16(ah[i], bh[j], acc[i][j], 0, 0, 0);
                acc[i][j] = __builtin_amdgcn_mfma_f32_16x16x32_bf16(ah[i], bl[j], acc[i][j], 0, 0, 0);
                acc[i][j] = __builtin_amdgcn_mfma_f32_16x16x32_bf16(al[i], bh[j], acc[i][j], 0, 0, 0);
            }
    }

#pragma unroll
    for (int i = 0; i < 4; ++i) {
#pragma unroll
        for (int r = 0; r < 4; ++r) {
            int row_g = bm + wm * 64 + i * 16 + (l >> 4) * 4 + r;
            if (row_g >= M) continue;
#pragma unroll
            for (int j = 0; j < 4; ++j) {
                int col_g = bn + wn * 64 + j * 16 + lr;
                Cb[(size_t)row_g * Nc + col_g] = f2bf(acc[i][j][r]);
            }
        }
    }
}

// ---------------- layers-2/3 GEMM: bf16 A (2 products: A*Wh + A*Wl) ----------------

__global__ __launch_bounds__(256) void gemm_bf16a_k(const unsigned short* __restrict__ A,
                                                    const unsigned short* __restrict__ Bh,
                                                    const unsigned short* __restrict__ Bl,
                                                    unsigned short* __restrict__ Cb,
                                                    int M, int K, int Nc) {
    __shared__ unsigned short As[128][GPAD];
    __shared__ unsigned short Bsh[128][GPAD];
    __shared__ unsigned short Bsl[128][GPAD];

    int bm = blockIdx.y * 128;
    int bn = blockIdx.x * 128;
    int t = threadIdx.x;
    int w = t >> 6, l = t & 63;
    int wm = w >> 1, wn = w & 1;
    int lr = l & 15, lk = (l >> 4) * 8;

    int srow = t >> 1;
    int skh  = (t & 1) * 16;

    f32x4 acc[4][4];
#pragma unroll
    for (int i = 0; i < 4; ++i)
#pragma unroll
        for (int j = 0; j < 4; ++j)
            acc[i][j] = (f32x4){0.f, 0.f, 0.f, 0.f};

    const int arow = bm + srow;
    const bool arow_ok = (arow < M);
    const size_t acol_base = (size_t)arow * K + skh;
    const size_t bcol_base = (size_t)(bn + srow) * K + skh;

    for (int k0 = 0; k0 < K; k0 += 32) {
        __syncthreads();   // protect previous iteration's fragment reads
        {
            uint4* da = reinterpret_cast<uint4*>(&As[srow][skh]);
            if (arow_ok) {
                const uint4* sa = reinterpret_cast<const uint4*>(A + acol_base + k0);
                da[0] = sa[0]; da[1] = sa[1];
            } else {
                da[0] = make_uint4(0u, 0u, 0u, 0u);
                da[1] = make_uint4(0u, 0u, 0u, 0u);
            }
            const uint4* sh = reinterpret_cast<const uint4*>(Bh + bcol_base + k0);
            const uint4* sl = reinterpret_cast<const uint4*>(Bl + bcol_base + k0);
            uint4* dh = reinterpret_cast<uint4*>(&Bsh[srow][skh]);
            uint4* dl = reinterpret_cast<uint4*>(&Bsl[srow][skh]);
            dh[0] = sh[0]; dh[1] = sh[1];
            dl[0] = sl[0]; dl[1] = sl[1];
        }
        __syncthreads();

        bf16x8 ah[4], bh[4], bl[4];
#pragma unroll
        for (int i = 0; i < 4; ++i) {
            int r = wm * 64 + i * 16 + lr;
            ah[i] = *reinterpret_cast<const bf16x8*>(&As[r][lk]);
        }
#pragma unroll
        for (int j = 0; j < 4; ++j) {
            int c = wn * 64 + j * 16 + lr;
            bh[j] = *reinterpret_cast<const bf16x8*>(&Bsh[c][lk]);
            bl[j] = *reinterpret_cast<const bf16x8*>(&Bsl[c][lk]);
        }
#pragma unroll
        for (int i = 0; i < 4; ++i)
#pragma unroll
            for (int j = 0; j < 4; ++j) {
                acc[i][j] = __builtin_amdgcn_mfma_f32_16x16x32_bf16(ah[i], bh[j], acc[i][j], 0, 0, 0);
                acc[i][j] = __builtin_amdgcn_mfma_f32_16x16x32_bf16(ah[i], bl[j], acc[i][j], 0, 0, 0);
            }
    }

#pragma unroll
    for (int i = 0; i < 4; ++i) {
#pragma unroll
        for (int r = 0; r < 4; ++r) {
            int row_g = bm + wm * 64 + i * 16 + (l >> 4) * 4 + r;
            if (row_g >= M) continue;
#pragma unroll
            for (int j = 0; j < 4; ++j) {
                int col_g = bn + wn * 64 + j * 16 + lr;
                Cb[(size_t)row_g * Nc + col_g] = f2bf(acc[i][j][r]);
            }
        }
    }
}

// ---------------- attention logit precompute: wave per node ----------------

__global__ __launch_bounds__(256) void compute_al_k(const unsigned short* __restrict__ h,
                                                    const float* __restrict__ a_src,
                                                    const float* __restrict__ a_dst,
                                                    float* __restrict__ al_s,
                                                    float* __restrict__ al_d, int n) {
    int wid = threadIdx.x >> 6, lane = threadIdx.x & 63;
    int node = blockIdx.x * 4 + wid;
    if (node >= n) return;
    ushort4 v = reinterpret_cast<const ushort4*>(h + (size_t)node * 256)[lane];
    float4 asv = reinterpret_cast<const float4*>(a_src)[lane];
    float4 adv = reinterpret_cast<const float4*>(a_dst)[lane];
    float ps = bf2f(v.x) * asv.x + bf2f(v.y) * asv.y + bf2f(v.z) * asv.z + bf2f(v.w) * asv.w;
    float pd = bf2f(v.x) * adv.x + bf2f(v.y) * adv.y + bf2f(v.z) * adv.z + bf2f(v.w) * adv.w;
#pragma unroll
    for (int off = 1; off < 8; off <<= 1) {
        ps += __shfl_xor(ps, off, 64);
        pd += __shfl_xor(pd, off, 64);
    }
    if ((lane & 7) == 0) {
        al_s[node * 8 + (lane >> 3)] = ps;
        al_d[node * 8 + (lane >> 3)] = pd;
    }
}

// layer 3: h [N,128] padded bf16, single head over 40 dims
__global__ void compute_al3_k(const unsigned short* __restrict__ h,
                              const float* __restrict__ a_src, const float* __restrict__ a_dst,
                              float* __restrict__ al_s, float* __restrict__ al_d, int n) {
    int wid = threadIdx.x >> 6, lane = threadIdx.x & 63;
    int node = blockIdx.x * 4 + wid;
    if (node >= n) return;
    float hv = (lane < 40) ? bf2f(h[(size_t)node * 128 + lane]) : 0.f;
    float ps = (lane < 40) ? hv * a_src[lane] : 0.f;
    float pd = (lane < 40) ? hv * a_dst[lane] : 0.f;
#pragma unroll
    for (int off = 32; off; off >>= 1) {
        ps += __shfl_xor(ps, off, 64);
        pd += __shfl_xor(pd, off, 64);
    }
    if (lane == 0) { al_s[node] = ps; al_d[node] = pd; }
}

// ---------------- edge softmax: one THREAD per (dst, head) ----------------

__global__ __launch_bounds__(256) void edge_softmax_k(const float* __restrict__ al_s,
                                                      const float* __restrict__ al_d,
                                                      const int* __restrict__ row_ptr,
                                                      const int* __restrict__ srcs,
                                                      float* __restrict__ w,
                                                      float* __restrict__ inv, int n8) {
    int tid = blockIdx.x * 256 + threadIdx.x;
    if (tid >= n8) return;
    int dst = tid >> 3, hd = tid & 7;
    int beg = row_ptr[dst], end = row_ptr[dst + 1];
    float ald = al_d[tid];

    float m = -1e30f;
    int i = beg;
    for (; i + 2 <= end; i += 2) {
        int s0 = srcs[i], s1 = srcs[i + 1];
        float l0 = al_s[s0 * 8 + hd] + ald;
        float l1 = al_s[s1 * 8 + hd] + ald;
        l0 = (l0 > 0.f) ? l0 : NEG_SLOPE * l0;
        l1 = (l1 > 0.f) ? l1 : NEG_SLOPE * l1;
        m = fmaxf(m, fmaxf(l0, l1));
    }
    if (i < end) {
        int s0 = srcs[i];
        float l0 = al_s[s0 * 8 + hd] + ald;
        l0 = (l0 > 0.f) ? l0 : NEG_SLOPE * l0;
        m = fmaxf(m, l0);
    }

    float sw = 0.f;
    for (i = beg; i < end; ++i) {
        int s = srcs[i];
        float l = al_s[s * 8 + hd] + ald;
        l = (l > 0.f) ? l : NEG_SLOPE * l;
        float e = __expf(l - m);
        w[(size_t)i * 8 + hd] = e;
        sw += e;
    }
    inv[tid] = 1.f / (sw + 1e-16f);
}

__global__ __launch_bounds__(256) void edge_softmax3_k(const float* __restrict__ al_s,
                                                       const float* __restrict__ al_d,
                                                       const int* __restrict__ row_ptr,
                                                       const int* __restrict__ srcs,
                                                       float* __restrict__ w,
                                                       float* __restrict__ inv, int n) {
    int dst = blockIdx.x * 256 + threadIdx.x;
    if (dst >= n) return;
    int beg = row_ptr[dst], end = row_ptr[dst + 1];
    float ald = al_d[dst];

    float m = -1e30f;
    int i = beg;
    for (; i + 2 <= end; i += 2) {
        int s0 = srcs[i], s1 = srcs[i + 1];
        float l0 = al_s[s0] + ald;
        float l1 = al_s[s1] + ald;
        l0 = (l0 > 0.f) ? l0 : NEG_SLOPE * l0;
        l1 = (l1 > 0.f) ? l1 : NEG_SLOPE * l1;
        m = fmaxf(m, fmaxf(l0, l1));
    }
    if (i < end) {
        int s0 = srcs[i];
        float l0 = al_s[s0] + ald;
        l0 = (l0 > 0.f) ? l0 : NEG_SLOPE * l0;
        m = fmaxf(m, l0);
    }

    float sw = 0.f;
    for (i = beg; i < end; ++i) {
        int s = srcs[i];
        float l = al_s[s] + ald;
        l = (l > 0.f) ? l : NEG_SLOPE * l;
        float e = __expf(l - m);
        w[i] = e;
        sw += e;
    }
    inv[dst] = 1.f / (sw + 1e-16f);
}

// ---------------- pure gather-FMA aggregation: one WAVE per dst -> bf16 out ----------------

template <bool ELU>
__global__ __launch_bounds__(256) void gat_gather_k(const unsigned short* __restrict__ h,
                                                    const float* __restrict__ w,
                                                    const float* __restrict__ inv,
                                                    const int* __restrict__ row_ptr,
                                                    const int* __restrict__ srcs,
                                                    const float* __restrict__ bias,
                                                    unsigned short* __restrict__ out, int n) {
    int wid = threadIdx.x >> 6, lane = threadIdx.x & 63;
    int dst = blockIdx.x * 4 + wid;
    if (dst >= n) return;
    int hd = lane >> 3;
    int beg = row_ptr[dst], end = row_ptr[dst + 1];
    const ushort4* hp = reinterpret_cast<const ushort4*>(h);

    float4 acc = make_float4(0.f, 0.f, 0.f, 0.f);
    int i = beg;
    for (; i + 4 <= end; i += 4) {
        int s0 = srcs[i + 0], s1 = srcs[i + 1], s2 = srcs[i + 2], s3 = srcs[i + 3];
        float w0 = w[(size_t)(i + 0) * 8 + hd];
        float w1 = w[(size_t)(i + 1) * 8 + hd];
        float w2 = w[(size_t)(i + 2) * 8 + hd];
        float w3 = w[(size_t)(i + 3) * 8 + hd];
        ushort4 v0 = hp[(size_t)s0 * 64 + lane];
        ushort4 v1 = hp[(size_t)s1 * 64 + lane];
        ushort4 v2 = hp[(size_t)s2 * 64 + lane];
        ushort4 v3 = hp[(size_t)s3 * 64 + lane];
        acc.x = fmaf(w0, bf2f(v0.x), acc.x);
        acc.y = fmaf(w0, bf2f(v0.y), acc.y);
        acc.z = fmaf(w0, bf2f(v0.z), acc.z);
        acc.w = fmaf(w0, bf2f(v0.w), acc.w);
        acc.x = fmaf(w1, bf2f(v1.x), acc.x);
        acc.y = fmaf(w1, bf2f(v1.y), acc.y);
        acc.z = fmaf(w1, bf2f(v1.z), acc.z);
        acc.w = fmaf(w1, bf2f(v1.w), acc.w);
        acc.x = fmaf(w2, bf2f(v2.x), acc.x);
        acc.y = fmaf(w2, bf2f(v2.y), acc.y);
        acc.z = fmaf(w2, bf2f(v2.z), acc.z);
        acc.w = fmaf(w2, bf2f(v2.w), acc.w);
        acc.x = fmaf(w3, bf2f(v3.x), acc.x);
        acc.y = fmaf(w3, bf2f(v3.y), acc.y);
        acc.z = fmaf(w3, bf2f(v3.z), acc.z);
        acc.w = fmaf(w3, bf2f(v3.w), acc.w);
    }
    for (; i < end; ++i) {
        int s = srcs[i];
        float wgt = w[(size_t)i * 8 + hd];
        ushort4 v = hp[(size_t)s * 64 + lane];
        acc.x = fmaf(wgt, bf2f(v.x), acc.x);
        acc.y = fmaf(wgt, bf2f(v.y), acc.y);
        acc.z = fmaf(wgt, bf2f(v.z), acc.z);
        acc.w = fmaf(wgt, bf2f(v.w), acc.w);
    }

    float iv = inv[dst * 8 + hd];
    float4 b4 = reinterpret_cast<const float4*>(bias)[lane];
    float4 o;
    o.x = acc.x * iv + b4.x;
    o.y = acc.y * iv + b4.y;
    o.z = acc.z * iv + b4.z;
    o.w = acc.w * iv + b4.w;
    if (ELU) {
        o.x = (o.x > 0.f) ? o.x : expm1f(o.x);
        o.y = (o.y > 0.f) ? o.y : expm1f(o.y);
        o.z = (o.z > 0.f) ? o.z : expm1f(o.z);
        o.w = (o.w > 0.f) ? o.w : expm1f(o.w);
    }
    ushort4 ob;
    ob.x = f2bf(o.x); ob.y = f2bf(o.y); ob.z = f2bf(o.z); ob.w = f2bf(o.w);
    reinterpret_cast<ushort4*>(out + (size_t)dst * 256)[lane] = ob;
}

// layer 3: wave per dst, 4 edges in parallel (16 lanes x ushort4 each), h [N,128] padded; fp32 out
__global__ __launch_bounds__(256) void gat_gather3_k(const unsigned short* __restrict__ h,
                                                     const float* __restrict__ w,
                                                     const float* __restrict__ inv,
                                                     const int* __restrict__ row_ptr,
                                                     const int* __restrict__ srcs,
                                                     const float* __restrict__ bias,
                                                     float* __restrict__ out, int n) {
    int wid = threadIdx.x >> 6, lane = threadIdx.x & 63;
    int dst = blockIdx.x * 4 + wid;
    if (dst >= n) return;
    int es = lane >> 4, cl = lane & 15;
    int beg = row_ptr[dst], end = row_ptr[dst + 1];

    float4 acc = make_float4(0.f, 0.f, 0.f, 0.f);
    for (int i = beg; i < end; i += 4) {
        int idx = i + es;
        bool ok = (idx < end);
        int s = ok ? srcs[idx] : srcs[beg];
        float wgt = ok ? w[idx] : 0.f;
        ushort4 v = reinterpret_cast<const ushort4*>(h + (size_t)s * 128)[cl];
        acc.x = fmaf(wgt, bf2f(v.x), acc.x);
        acc.y = fmaf(wgt, bf2f(v.y), acc.y);
        acc.z = fmaf(wgt, bf2f(v.z), acc.z);
        acc.w = fmaf(wgt, bf2f(v.w), acc.w);
    }
#pragma unroll
    for (int off = 16; off <= 32; off <<= 1) {
        acc.x += __shfl_xor(acc.x, off, 64);
        acc.y += __shfl_xor(acc.y, off, 64);
        acc.z += __shfl_xor(acc.z, off, 64);
        acc.w += __shfl_xor(acc.w, off, 64);
    }
    if (es == 0 && cl < 10) {
        float iv = inv[dst];
        int c = cl * 4;
        float4 b4 = *reinterpret_cast<const float4*>(bias + c);
        float4 o;
        o.x = acc.x * iv + b4.x;
        o.y = acc.y * iv + b4.y;
        o.z = acc.z * iv + b4.z;
        o.w = acc.w * iv + b4.w;
        *reinterpret_cast<float4*>(out + (size_t)dst * 40 + c) = o;
    }
}

// ---------------- launch ----------------

extern "C" void kernel_launch(void* const* d_in, const int* in_sizes, int n_in,
                              void* d_out, int out_size, void* d_ws, size_t ws_size,
                              hipStream_t stream) {
    const float* x   = (const float*)d_in[0];
    const int*   ei  = (const int*)d_in[1];
    const float* W1  = (const float*)d_in[2];
    const float* as1 = (const float*)d_in[3];
    const float* ad1 = (const float*)d_in[4];
    const float* b1  = (const float*)d_in[5];
    const float* W2  = (const float*)d_in[6];
    const float* as2 = (const float*)d_in[7];
    const float* ad2 = (const float*)d_in[8];
    const float* b2  = (const float*)d_in[9];
    const float* W3  = (const float*)d_in[10];
    const float* as3 = (const float*)d_in[11];
    const float* ad3 = (const float*)d_in[12];
    const float* b3  = (const float*)d_in[13];

    const int N = in_sizes[0] / 128;   // 50000
    const int E = in_sizes[1] / 2;     // 800000
    const int ET = E + N;

    char* ws = (char*)d_ws;
    size_t off = 0;
    auto alloc = [&](size_t bytes) -> void* {
        void* p = ws + off;
        off += (bytes + 255) & ~(size_t)255;
        return p;
    };
    int*   row_ptr = (int*)alloc(sizeof(int) * (N + 1));
    int*   pos     = (int*)alloc(sizeof(int) * N);
    int*   srcs    = (int*)alloc(sizeof(int) * ET);
    int*   bsums   = (int*)alloc(sizeof(int) * 64);
    float* als     = (float*)alloc(sizeof(float) * N * 8);
    float* ald     = (float*)alloc(sizeof(float) * N * 8);
    float* wbuf    = (float*)alloc(sizeof(float) * (size_t)ET * 8);
    float* invb    = (float*)alloc(sizeof(float) * N * 8);
    unsigned short* hb16 = (unsigned short*)alloc(sizeof(unsigned short) * (size_t)N * 256);
    unsigned short* ab16 = (unsigned short*)alloc(sizeof(unsigned short) * (size_t)N * 256);
    unsigned short* wbh  = (unsigned short*)alloc(sizeof(unsigned short) * 256 * 256);
    unsigned short* wbl  = (unsigned short*)alloc(sizeof(unsigned short) * 256 * 256);
    (void)ws_size;

    const int nb = (N + 1023) / 1024;

    // --- CSR build ---
    hipMemsetAsync(pos, 0, sizeof(int) * N, stream);
    count_edges_k<<<(ET + 255) / 256, 256, 0, stream>>>(ei, E, N, pos);
    scan1_k<<<nb, 256, 0, stream>>>(pos, row_ptr, bsums, N);
    scan2_k<<<1, 64, 0, stream>>>(bsums, nb);
    scan3_k<<<(N + 1 + 255) / 256, 256, 0, stream>>>(row_ptr, pos, bsums, N, ET);
    scatter_edges_k<<<(ET + 255) / 256, 256, 0, stream>>>(ei, E, N, pos, srcs);

    const int gy = (N + 127) / 128;
    const int gagg = (N + 3) / 4;
    const int gsm = (N * 8 + 255) / 256;

    // --- layer 1: x[N,128] @ W1[128,256] (fp32-A split, 3 products) -> bf16 h ---
    convert_w_k<<<(128 * 256 + 255) / 256, 256, 0, stream>>>(W1, wbh, wbl, 128, 256);
    mfma_gemm_k<<<dim3(2, gy), 256, 0, stream>>>(x, wbh, wbl, hb16, N, 128, 256);
    compute_al_k<<<gagg, 256, 0, stream>>>(hb16, as1, ad1, als, ald, N);
    edge_softmax_k<<<gsm, 256, 0, stream>>>(als, ald, row_ptr, srcs, wbuf, invb, N * 8);
    gat_gather_k<true><<<gagg, 256, 0, stream>>>(hb16, wbuf, invb, row_ptr, srcs, b1, ab16, N);

    // --- layer 2: ab16[N,256] @ W2[256,256] (bf16-A, 2 products) ---
    convert_w_k<<<(256 * 256 + 255) / 256, 256, 0, stream>>>(W2, wbh, wbl, 256, 256);
    gemm_bf16a_k<<<dim3(2, gy), 256, 0, stream>>>(ab16, wbh, wbl, hb16, N, 256, 256);
    compute_al_k<<<gagg, 256, 0, stream>>>(hb16, as2, ad2, als, ald, N);
    edge_softmax_k<<<gsm, 256, 0, stream>>>(als, ald, row_ptr, srcs, wbuf, invb, N * 8);
    gat_gather_k<true><<<gagg, 256, 0, stream>>>(hb16, wbuf, invb, row_ptr, srcs, b2, ab16, N);

    // --- layer 3: ab16[N,256] @ W3[256,40] (cols padded to 128) -> h3 [N,128] bf16 ---
    hipMemsetAsync(wbh, 0, sizeof(unsigned short) * 128 * 256, stream);
    hipMemsetAsync(wbl, 0, sizeof(unsigned short) * 128 * 256, stream);
    convert_w_k<<<(256 * 40 + 255) / 256, 256, 0, stream>>>(W3, wbh, wbl, 256, 40);
    gemm_bf16a_k<<<dim3(1, gy), 256, 0, stream>>>(ab16, wbh, wbl, hb16, N, 256, 128);
    compute_al3_k<<<gagg, 256, 0, stream>>>(hb16, as3, ad3, als, ald, N);
    edge_softmax3_k<<<(N + 255) / 256, 256, 0, stream>>>(als, ald, row_ptr, srcs, wbuf, invb, N);
    gat_gather3_k<<<gagg, 256, 0, stream>>>(hb16, wbuf, invb, row_ptr, srcs, b3, (float*)d_out, N);
}

// Round 8
// 427.597 us; speedup vs baseline: 1.6085x; 1.0386x over previous
//
#include <hip/hip_runtime.h>
#include <hip/hip_bf16.h>

#define NEG_SLOPE 0.2f

typedef __attribute__((ext_vector_type(8))) short bf16x8;
typedef __attribute__((ext_vector_type(4))) float f32x4;

__device__ __forceinline__ unsigned short f2bf(float v) {
    union { float f; unsigned int u; } x; x.f = v;
    unsigned int r = x.u + 0x7fffu + ((x.u >> 16) & 1u);
    return (unsigned short)(r >> 16);
}
__device__ __forceinline__ float bf2f(unsigned short b) {
    union { unsigned int u; float f; } x; x.u = ((unsigned int)b) << 16;
    return x.f;
}

// ---------------- CSR build ----------------

__global__ void count_edges_k(const int* __restrict__ ei, int E, int n, int* __restrict__ cnt) {
    int e = blockIdx.x * 256 + threadIdx.x;
    int ET = E + n;
    if (e >= ET) return;
    int d = (e < E) ? ei[E + e] : (e - E);
    atomicAdd(&cnt[d], 1);
}

__global__ void scan1_k(const int* __restrict__ cnt, int* __restrict__ row_ptr,
                        int* __restrict__ bsums, int n) {
    __shared__ int sd[256];
    int b = blockIdx.x, t = threadIdx.x;
    int base = b * 1024 + t * 4;
    int v[4];
    int loc = 0;
#pragma unroll
    for (int j = 0; j < 4; ++j) {
        v[j] = (base + j < n) ? cnt[base + j] : 0;
        loc += v[j];
    }
    sd[t] = loc;
    __syncthreads();
    for (int off = 1; off < 256; off <<= 1) {
        int x = (t >= off) ? sd[t - off] : 0;
        __syncthreads();
        sd[t] += x;
        __syncthreads();
    }
    int run = sd[t] - loc;
    if (t == 255) bsums[b] = sd[t];
#pragma unroll
    for (int j = 0; j < 4; ++j) {
        if (base + j < n) row_ptr[base + j] = run;
        run += v[j];
    }
}

__global__ void scan2_k(int* __restrict__ bsums, int nb) {
    if (threadIdx.x == 0 && blockIdx.x == 0) {
        int run = 0;
        for (int i = 0; i < nb; ++i) { int x = bsums[i]; bsums[i] = run; run += x; }
    }
}

__global__ void scan3_k(int* __restrict__ row_ptr, int* __restrict__ pos,
                        const int* __restrict__ bsums, int n, int total) {
    int idx = blockIdx.x * 256 + threadIdx.x;
    if (idx < n) {
        int vv = row_ptr[idx] + bsums[idx >> 10];
        row_ptr[idx] = vv;
        pos[idx] = vv;
    } else if (idx == n) {
        row_ptr[n] = total;
    }
}

__global__ void scatter_edges_k(const int* __restrict__ ei, int E, int n,
                                int* __restrict__ pos, int* __restrict__ srcs) {
    int e = blockIdx.x * 256 + threadIdx.x;
    int ET = E + n;
    if (e >= ET) return;
    int s, d;
    if (e < E) { s = ei[e]; d = ei[E + e]; }
    else       { s = e - E; d = e - E; }
    int idx = atomicAdd(&pos[d], 1);
    srcs[idx] = s;
}

// ---------------- weight pre-convert (all layers, one launch) ----------------
// W[K][Nc] fp32 -> col-major hi/lo bf16 [Nc][K]; W3 zero-padded 40 -> 128 cols.

#define R1 (128 * 256)
#define R2 (256 * 256)
#define R3 (256 * 128)

__global__ void convert_w_all_k(const float* __restrict__ W1, const float* __restrict__ W2,
                                const float* __restrict__ W3,
                                unsigned short* __restrict__ b1h, unsigned short* __restrict__ b1l,
                                unsigned short* __restrict__ b2h, unsigned short* __restrict__ b2l,
                                unsigned short* __restrict__ b3h, unsigned short* __restrict__ b3l) {
    int idx = blockIdx.x * 256 + threadIdx.x;
    float v;
    unsigned short* dh;
    unsigned short* dl;
    int o;
    if (idx < R1) {
        int k = idx >> 8, c = idx & 255;           // K=128, Nc=256
        v = W1[idx]; dh = b1h; dl = b1l; o = c * 128 + k;
    } else if (idx < R1 + R2) {
        int j = idx - R1;
        int k = j >> 8, c = j & 255;               // K=256, Nc=256
        v = W2[j]; dh = b2h; dl = b2l; o = c * 256 + k;
    } else if (idx < R1 + R2 + R3) {
        int j = idx - (R1 + R2);
        int k = j >> 7, c = j & 127;               // K=256, Nc=128 (pad >=40 with 0)
        v = (c < 40) ? W3[k * 40 + c] : 0.f;
        dh = b3h; dl = b3l; o = c * 256 + k;
    } else {
        return;
    }
    unsigned short h = f2bf(v);
    dh[o] = h;
    dl[o] = f2bf(v - bf2f(h));
}

// ---------------- layer-1 GEMM: fp32 A split on the fly (3 products) ----------------

#define GPAD 40

__global__ __launch_bounds__(256) void mfma_gemm_k(const float* __restrict__ A,
                                                   const unsigned short* __restrict__ Bh,
                                                   const unsigned short* __restrict__ Bl,
                                                   unsigned short* __restrict__ Cb,
                                                   int M, int K, int Nc) {
    __shared__ unsigned short Ash[128][GPAD];
    __shared__ unsigned short Asl[128][GPAD];
    __shared__ unsigned short Bsh[128][GPAD];
    __shared__ unsigned short Bsl[128][GPAD];

    int bm = blockIdx.y * 128;
    int bn = blockIdx.x * 128;
    int t = threadIdx.x;
    int w = t >> 6, l = t & 63;
    int wm = w >> 1, wn = w & 1;
    int lr = l & 15, lk = (l >> 4) * 8;

    int srow = t >> 1;
    int skh  = (t & 1) * 16;

    f32x4 acc[4][4];
#pragma unroll
    for (int i = 0; i < 4; ++i)
#pragma unroll
        for (int j = 0; j < 4; ++j)
            acc[i][j] = (f32x4){0.f, 0.f, 0.f, 0.f};

    const int arow = bm + srow;
    const bool arow_ok = (arow < M);
    const size_t acol_base = (size_t)arow * K + skh;
    const size_t bcol_base = (size_t)(bn + srow) * K + skh;

    for (int k0 = 0; k0 < K; k0 += 32) {
        float vv[16];
        if (arow_ok) {
            const float4* ap = reinterpret_cast<const float4*>(A + acol_base + k0);
#pragma unroll
            for (int q = 0; q < 4; ++q) {
                float4 v4 = ap[q];
                vv[4 * q + 0] = v4.x; vv[4 * q + 1] = v4.y;
                vv[4 * q + 2] = v4.z; vv[4 * q + 3] = v4.w;
            }
        } else {
#pragma unroll
            for (int q = 0; q < 16; ++q) vv[q] = 0.f;
        }
        unsigned int hw[8], lw[8];
#pragma unroll
        for (int q = 0; q < 8; ++q) {
            unsigned short h0 = f2bf(vv[2 * q]);
            unsigned short h1 = f2bf(vv[2 * q + 1]);
            unsigned short l0 = f2bf(vv[2 * q] - bf2f(h0));
            unsigned short l1 = f2bf(vv[2 * q + 1] - bf2f(h1));
            hw[q] = (unsigned int)h0 | ((unsigned int)h1 << 16);
            lw[q] = (unsigned int)l0 | ((unsigned int)l1 << 16);
        }
        __syncthreads();
        {
            uint4* dh = reinterpret_cast<uint4*>(&Ash[srow][skh]);
            uint4* dl = reinterpret_cast<uint4*>(&Asl[srow][skh]);
            dh[0] = make_uint4(hw[0], hw[1], hw[2], hw[3]);
            dh[1] = make_uint4(hw[4], hw[5], hw[6], hw[7]);
            dl[0] = make_uint4(lw[0], lw[1], lw[2], lw[3]);
            dl[1] = make_uint4(lw[4], lw[5], lw[6], lw[7]);
        }
        {
            const uint4* sh = reinterpret_cast<const uint4*>(Bh + bcol_base + k0);
            const uint4* sl = reinterpret_cast<const uint4*>(Bl + bcol_base + k0);
            uint4* dh = reinterpret_cast<uint4*>(&Bsh[srow][skh]);
            uint4* dl = reinterpret_cast<uint4*>(&Bsl[srow][skh]);
            dh[0] = sh[0]; dh[1] = sh[1];
            dl[0] = sl[0]; dl[1] = sl[1];
        }
        __syncthreads();

        bf16x8 ah[4], al[4], bh[4], bl[4];
#pragma unroll
        for (int i = 0; i < 4; ++i) {
            int r = wm * 64 + i * 16 + lr;
            ah[i] = *reinterpret_cast<const bf16x8*>(&Ash[r][lk]);
            al[i] = *reinterpret_cast<const bf16x8*>(&Asl[r][lk]);
        }
#pragma unroll
        for (int j = 0; j < 4; ++j) {
            int c = wn * 64 + j * 16 + lr;
            bh[j] = *reinterpret_cast<const bf16x8*>(&Bsh[c][lk]);
            bl[j] = *reinterpret_cast<const bf16x8*>(&Bsl[c][lk]);
        }
#pragma unroll
        for (int i = 0; i < 4; ++i)
#pragma unroll
            for (int j = 0; j < 4; ++j) {
                acc[i][j] = __builtin_amdgcn_mfma_f32_16x16x32_bf16(ah[i], bh[j], acc[i][j], 0, 0, 0);
                acc[i][j] = __builtin_amdgcn_mfma_f32_16x16x32_bf16(ah[i], bl[j], acc[i][j], 0, 0, 0);
                acc[i][j] = __builtin_amdgcn_mfma_f32_16x16x32_bf16(al[i], bh[j], acc[i][j], 0, 0, 0);
            }
    }

#pragma unroll
    for (int i = 0; i < 4; ++i) {
#pragma unroll
        for (int r = 0; r < 4; ++r) {
            int row_g = bm + wm * 64 + i * 16 + (l >> 4) * 4 + r;
            if (row_g >= M) continue;
#pragma unroll
            for (int j = 0; j < 4; ++j) {
                int col_g = bn + wn * 64 + j * 16 + lr;
                Cb[(size_t)row_g * Nc + col_g] = f2bf(acc[i][j][r]);
            }
        }
    }
}

// ---------------- layers-2/3 GEMM: bf16 A (2 products: A*Wh + A*Wl) ----------------

__global__ __launch_bounds__(256) void gemm_bf16a_k(const unsigned short* __restrict__ A,
                                                    const unsigned short* __restrict__ Bh,
                                                    const unsigned short* __restrict__ Bl,
                                                    unsigned short* __restrict__ Cb,
                                                    int M, int K, int Nc) {
    __shared__ unsigned short As[128][GPAD];
    __shared__ unsigned short Bsh[128][GPAD];
    __shared__ unsigned short Bsl[128][GPAD];

    int bm = blockIdx.y * 128;
    int bn = blockIdx.x * 128;
    int t = threadIdx.x;
    int w = t >> 6, l = t & 63;
    int wm = w >> 1, wn = w & 1;
    int lr = l & 15, lk = (l >> 4) * 8;

    int srow = t >> 1;
    int skh  = (t & 1) * 16;

    f32x4 acc[4][4];
#pragma unroll
    for (int i = 0; i < 4; ++i)
#pragma unroll
        for (int j = 0; j < 4; ++j)
            acc[i][j] = (f32x4){0.f, 0.f, 0.f, 0.f};

    const int arow = bm + srow;
    const bool arow_ok = (arow < M);
    const size_t acol_base = (size_t)arow * K + skh;
    const size_t bcol_base = (size_t)(bn + srow) * K + skh;

    for (int k0 = 0; k0 < K; k0 += 32) {
        __syncthreads();
        {
            uint4* da = reinterpret_cast<uint4*>(&As[srow][skh]);
            if (arow_ok) {
                const uint4* sa = reinterpret_cast<const uint4*>(A + acol_base + k0);
                da[0] = sa[0]; da[1] = sa[1];
            } else {
                da[0] = make_uint4(0u, 0u, 0u, 0u);
                da[1] = make_uint4(0u, 0u, 0u, 0u);
            }
            const uint4* sh = reinterpret_cast<const uint4*>(Bh + bcol_base + k0);
            const uint4* sl = reinterpret_cast<const uint4*>(Bl + bcol_base + k0);
            uint4* dh = reinterpret_cast<uint4*>(&Bsh[srow][skh]);
            uint4* dl = reinterpret_cast<uint4*>(&Bsl[srow][skh]);
            dh[0] = sh[0]; dh[1] = sh[1];
            dl[0] = sl[0]; dl[1] = sl[1];
        }
        __syncthreads();

        bf16x8 ah[4], bh[4], bl[4];
#pragma unroll
        for (int i = 0; i < 4; ++i) {
            int r = wm * 64 + i * 16 + lr;
            ah[i] = *reinterpret_cast<const bf16x8*>(&As[r][lk]);
        }
#pragma unroll
        for (int j = 0; j < 4; ++j) {
            int c = wn * 64 + j * 16 + lr;
            bh[j] = *reinterpret_cast<const bf16x8*>(&Bsh[c][lk]);
            bl[j] = *reinterpret_cast<const bf16x8*>(&Bsl[c][lk]);
        }
#pragma unroll
        for (int i = 0; i < 4; ++i)
#pragma unroll
            for (int j = 0; j < 4; ++j) {
                acc[i][j] = __builtin_amdgcn_mfma_f32_16x16x32_bf16(ah[i], bh[j], acc[i][j], 0, 0, 0);
                acc[i][j] = __builtin_amdgcn_mfma_f32_16x16x32_bf16(ah[i], bl[j], acc[i][j], 0, 0, 0);
            }
    }

#pragma unroll
    for (int i = 0; i < 4; ++i) {
#pragma unroll
        for (int r = 0; r < 4; ++r) {
            int row_g = bm + wm * 64 + i * 16 + (l >> 4) * 4 + r;
            if (row_g >= M) continue;
#pragma unroll
            for (int j = 0; j < 4; ++j) {
                int col_g = bn + wn * 64 + j * 16 + lr;
                Cb[(size_t)row_g * Nc + col_g] = f2bf(acc[i][j][r]);
            }
        }
    }
}

// ---------------- attention logit precompute: persistent wave per node ----------------

__global__ __launch_bounds__(256) void compute_al_k(const unsigned short* __restrict__ h,
                                                    const float* __restrict__ a_src,
                                                    const float* __restrict__ a_dst,
                                                    float* __restrict__ al_s,
                                                    float* __restrict__ al_d, int n) {
    int gw = blockIdx.x * 4 + (threadIdx.x >> 6);
    int nw = gridDim.x * 4;
    int lane = threadIdx.x & 63;
    float4 asv = reinterpret_cast<const float4*>(a_src)[lane];
    float4 adv = reinterpret_cast<const float4*>(a_dst)[lane];
    for (int node = gw; node < n; node += nw) {
        ushort4 v = reinterpret_cast<const ushort4*>(h + (size_t)node * 256)[lane];
        float ps = bf2f(v.x) * asv.x + bf2f(v.y) * asv.y + bf2f(v.z) * asv.z + bf2f(v.w) * asv.w;
        float pd = bf2f(v.x) * adv.x + bf2f(v.y) * adv.y + bf2f(v.z) * adv.z + bf2f(v.w) * adv.w;
#pragma unroll
        for (int off = 1; off < 8; off <<= 1) {
            ps += __shfl_xor(ps, off, 64);
            pd += __shfl_xor(pd, off, 64);
        }
        if ((lane & 7) == 0) {
            al_s[node * 8 + (lane >> 3)] = ps;
            al_d[node * 8 + (lane >> 3)] = pd;
        }
    }
}

// layer 3: h [N,128] padded bf16, single head over 40 dims
__global__ void compute_al3_k(const unsigned short* __restrict__ h,
                              const float* __restrict__ a_src, const float* __restrict__ a_dst,
                              float* __restrict__ al_s, float* __restrict__ al_d, int n) {
    int wid = threadIdx.x >> 6, lane = threadIdx.x & 63;
    int node = blockIdx.x * 4 + wid;
    if (node >= n) return;
    float hv = (lane < 40) ? bf2f(h[(size_t)node * 128 + lane]) : 0.f;
    float ps = (lane < 40) ? hv * a_src[lane] : 0.f;
    float pd = (lane < 40) ? hv * a_dst[lane] : 0.f;
#pragma unroll
    for (int off = 32; off; off >>= 1) {
        ps += __shfl_xor(ps, off, 64);
        pd += __shfl_xor(pd, off, 64);
    }
    if (lane == 0) { al_s[node] = ps; al_d[node] = pd; }
}

// ---------------- edge softmax: one THREAD per (dst, head) ----------------

__global__ __launch_bounds__(256) void edge_softmax_k(const float* __restrict__ al_s,
                                                      const float* __restrict__ al_d,
                                                      const int* __restrict__ row_ptr,
                                                      const int* __restrict__ srcs,
                                                      float* __restrict__ w,
                                                      float* __restrict__ inv, int n8) {
    int tid = blockIdx.x * 256 + threadIdx.x;
    if (tid >= n8) return;
    int dst = tid >> 3, hd = tid & 7;
    int beg = row_ptr[dst], end = row_ptr[dst + 1];
    float ald = al_d[tid];

    float m = -1e30f;
    int i = beg;
    for (; i + 2 <= end; i += 2) {
        int s0 = srcs[i], s1 = srcs[i + 1];
        float l0 = al_s[s0 * 8 + hd] + ald;
        float l1 = al_s[s1 * 8 + hd] + ald;
        l0 = (l0 > 0.f) ? l0 : NEG_SLOPE * l0;
        l1 = (l1 > 0.f) ? l1 : NEG_SLOPE * l1;
        m = fmaxf(m, fmaxf(l0, l1));
    }
    if (i < end) {
        int s0 = srcs[i];
        float l0 = al_s[s0 * 8 + hd] + ald;
        l0 = (l0 > 0.f) ? l0 : NEG_SLOPE * l0;
        m = fmaxf(m, l0);
    }

    float sw = 0.f;
    i = beg;
    for (; i + 2 <= end; i += 2) {
        int s0 = srcs[i], s1 = srcs[i + 1];
        float l0 = al_s[s0 * 8 + hd] + ald;
        float l1 = al_s[s1 * 8 + hd] + ald;
        l0 = (l0 > 0.f) ? l0 : NEG_SLOPE * l0;
        l1 = (l1 > 0.f) ? l1 : NEG_SLOPE * l1;
        float e0 = __expf(l0 - m);
        float e1 = __expf(l1 - m);
        w[(size_t)i * 8 + hd] = e0;
        w[(size_t)(i + 1) * 8 + hd] = e1;
        sw += e0 + e1;
    }
    if (i < end) {
        int s = srcs[i];
        float l = al_s[s * 8 + hd] + ald;
        l = (l > 0.f) ? l : NEG_SLOPE * l;
        float e = __expf(l - m);
        w[(size_t)i * 8 + hd] = e;
        sw += e;
    }
    inv[tid] = 1.f / (sw + 1e-16f);
}

__global__ __launch_bounds__(256) void edge_softmax3_k(const float* __restrict__ al_s,
                                                       const float* __restrict__ al_d,
                                                       const int* __restrict__ row_ptr,
                                                       const int* __restrict__ srcs,
                                                       float* __restrict__ w,
                                                       float* __restrict__ inv, int n) {
    int dst = blockIdx.x * 256 + threadIdx.x;
    if (dst >= n) return;
    int beg = row_ptr[dst], end = row_ptr[dst + 1];
    float ald = al_d[dst];

    float m = -1e30f;
    int i = beg;
    for (; i + 2 <= end; i += 2) {
        int s0 = srcs[i], s1 = srcs[i + 1];
        float l0 = al_s[s0] + ald;
        float l1 = al_s[s1] + ald;
        l0 = (l0 > 0.f) ? l0 : NEG_SLOPE * l0;
        l1 = (l1 > 0.f) ? l1 : NEG_SLOPE * l1;
        m = fmaxf(m, fmaxf(l0, l1));
    }
    if (i < end) {
        int s0 = srcs[i];
        float l0 = al_s[s0] + ald;
        l0 = (l0 > 0.f) ? l0 : NEG_SLOPE * l0;
        m = fmaxf(m, l0);
    }

    float sw = 0.f;
    for (i = beg; i < end; ++i) {
        int s = srcs[i];
        float l = al_s[s] + ald;
        l = (l > 0.f) ? l : NEG_SLOPE * l;
        float e = __expf(l - m);
        w[i] = e;
        sw += e;
    }
    inv[dst] = 1.f / (sw + 1e-16f);
}

// ---------------- pure gather-FMA aggregation: persistent wave per dst -> bf16 out ----------------

template <bool ELU>
__global__ __launch_bounds__(256) void gat_gather_k(const unsigned short* __restrict__ h,
                                                    const float* __restrict__ w,
                                                    const float* __restrict__ inv,
                                                    const int* __restrict__ row_ptr,
                                                    const int* __restrict__ srcs,
                                                    const float* __restrict__ bias,
                                                    unsigned short* __restrict__ out, int n) {
    int gw = blockIdx.x * 4 + (threadIdx.x >> 6);
    int nw = gridDim.x * 4;
    int lane = threadIdx.x & 63;
    int hd = lane >> 3;
    const ushort4* hp = reinterpret_cast<const ushort4*>(h);
    float4 b4 = reinterpret_cast<const float4*>(bias)[lane];

    for (int dst = gw; dst < n; dst += nw) {
        int beg = row_ptr[dst], end = row_ptr[dst + 1];
        float4 acc = make_float4(0.f, 0.f, 0.f, 0.f);
        int i = beg;
        for (; i + 4 <= end; i += 4) {
            int s0 = srcs[i + 0], s1 = srcs[i + 1], s2 = srcs[i + 2], s3 = srcs[i + 3];
            float w0 = w[(size_t)(i + 0) * 8 + hd];
            float w1 = w[(size_t)(i + 1) * 8 + hd];
            float w2 = w[(size_t)(i + 2) * 8 + hd];
            float w3 = w[(size_t)(i + 3) * 8 + hd];
            ushort4 v0 = hp[(size_t)s0 * 64 + lane];
            ushort4 v1 = hp[(size_t)s1 * 64 + lane];
            ushort4 v2 = hp[(size_t)s2 * 64 + lane];
            ushort4 v3 = hp[(size_t)s3 * 64 + lane];
            acc.x = fmaf(w0, bf2f(v0.x), acc.x);
            acc.y = fmaf(w0, bf2f(v0.y), acc.y);
            acc.z = fmaf(w0, bf2f(v0.z), acc.z);
            acc.w = fmaf(w0, bf2f(v0.w), acc.w);
            acc.x = fmaf(w1, bf2f(v1.x), acc.x);
            acc.y = fmaf(w1, bf2f(v1.y), acc.y);
            acc.z = fmaf(w1, bf2f(v1.z), acc.z);
            acc.w = fmaf(w1, bf2f(v1.w), acc.w);
            acc.x = fmaf(w2, bf2f(v2.x), acc.x);
            acc.y = fmaf(w2, bf2f(v2.y), acc.y);
            acc.z = fmaf(w2, bf2f(v2.z), acc.z);
            acc.w = fmaf(w2, bf2f(v2.w), acc.w);
            acc.x = fmaf(w3, bf2f(v3.x), acc.x);
            acc.y = fmaf(w3, bf2f(v3.y), acc.y);
            acc.z = fmaf(w3, bf2f(v3.z), acc.z);
            acc.w = fmaf(w3, bf2f(v3.w), acc.w);
        }
        for (; i < end; ++i) {
            int s = srcs[i];
            float wgt = w[(size_t)i * 8 + hd];
            ushort4 v = hp[(size_t)s * 64 + lane];
            acc.x = fmaf(wgt, bf2f(v.x), acc.x);
            acc.y = fmaf(wgt, bf2f(v.y), acc.y);
            acc.z = fmaf(wgt, bf2f(v.z), acc.z);
            acc.w = fmaf(wgt, bf2f(v.w), acc.w);
        }

        float iv = inv[dst * 8 + hd];
        float4 o;
        o.x = acc.x * iv + b4.x;
        o.y = acc.y * iv + b4.y;
        o.z = acc.z * iv + b4.z;
        o.w = acc.w * iv + b4.w;
        if (ELU) {
            o.x = (o.x > 0.f) ? o.x : expm1f(o.x);
            o.y = (o.y > 0.f) ? o.y : expm1f(o.y);
            o.z = (o.z > 0.f) ? o.z : expm1f(o.z);
            o.w = (o.w > 0.f) ? o.w : expm1f(o.w);
        }
        ushort4 ob;
        ob.x = f2bf(o.x); ob.y = f2bf(o.y); ob.z = f2bf(o.z); ob.w = f2bf(o.w);
        reinterpret_cast<ushort4*>(out + (size_t)dst * 256)[lane] = ob;
    }
}

// layer 3: persistent wave per dst, 4 edges in parallel (16 lanes x ushort4 each); fp32 out
__global__ __launch_bounds__(256) void gat_gather3_k(const unsigned short* __restrict__ h,
                                                     const float* __restrict__ w,
                                                     const float* __restrict__ inv,
                                                     const int* __restrict__ row_ptr,
                                                     const int* __restrict__ srcs,
                                                     const float* __restrict__ bias,
                                                     float* __restrict__ out, int n) {
    int gw = blockIdx.x * 4 + (threadIdx.x >> 6);
    int nw = gridDim.x * 4;
    int lane = threadIdx.x & 63;
    int es = lane >> 4, cl = lane & 15;

    for (int dst = gw; dst < n; dst += nw) {
        int beg = row_ptr[dst], end = row_ptr[dst + 1];
        float4 acc = make_float4(0.f, 0.f, 0.f, 0.f);
        for (int i = beg; i < end; i += 4) {
            int idx = i + es;
            bool ok = (idx < end);
            int s = ok ? srcs[idx] : srcs[beg];
            float wgt = ok ? w[idx] : 0.f;
            ushort4 v = reinterpret_cast<const ushort4*>(h + (size_t)s * 128)[cl];
            acc.x = fmaf(wgt, bf2f(v.x), acc.x);
            acc.y = fmaf(wgt, bf2f(v.y), acc.y);
            acc.z = fmaf(wgt, bf2f(v.z), acc.z);
            acc.w = fmaf(wgt, bf2f(v.w), acc.w);
        }
#pragma unroll
        for (int off = 16; off <= 32; off <<= 1) {
            acc.x += __shfl_xor(acc.x, off, 64);
            acc.y += __shfl_xor(acc.y, off, 64);
            acc.z += __shfl_xor(acc.z, off, 64);
            acc.w += __shfl_xor(acc.w, off, 64);
        }
        if (es == 0 && cl < 10) {
            float iv = inv[dst];
            int c = cl * 4;
            float4 b4 = *reinterpret_cast<const float4*>(bias + c);
            float4 o;
            o.x = acc.x * iv + b4.x;
            o.y = acc.y * iv + b4.y;
            o.z = acc.z * iv + b4.z;
            o.w = acc.w * iv + b4.w;
            *reinterpret_cast<float4*>(out + (size_t)dst * 40 + c) = o;
        }
    }
}

// ---------------- launch ----------------

extern "C" void kernel_launch(void* const* d_in, const int* in_sizes, int n_in,
                              void* d_out, int out_size, void* d_ws, size_t ws_size,
                              hipStream_t stream) {
    const float* x   = (const float*)d_in[0];
    const int*   ei  = (const int*)d_in[1];
    const float* W1  = (const float*)d_in[2];
    const float* as1 = (const float*)d_in[3];
    const float* ad1 = (const float*)d_in[4];
    const float* b1  = (const float*)d_in[5];
    const float* W2  = (const float*)d_in[6];
    const float* as2 = (const float*)d_in[7];
    const float* ad2 = (const float*)d_in[8];
    const float* b2  = (const float*)d_in[9];
    const float* W3  = (const float*)d_in[10];
    const float* as3 = (const float*)d_in[11];
    const float* ad3 = (const float*)d_in[12];
    const float* b3  = (const float*)d_in[13];

    const int N = in_sizes[0] / 128;   // 50000
    const int E = in_sizes[1] / 2;     // 800000
    const int ET = E + N;

    char* ws = (char*)d_ws;
    size_t off = 0;
    auto alloc = [&](size_t bytes) -> void* {
        void* p = ws + off;
        off += (bytes + 255) & ~(size_t)255;
        return p;
    };
    int*   row_ptr = (int*)alloc(sizeof(int) * (N + 1));
    int*   pos     = (int*)alloc(sizeof(int) * N);
    int*   srcs    = (int*)alloc(sizeof(int) * ET);
    int*   bsums   = (int*)alloc(sizeof(int) * 64);
    float* als     = (float*)alloc(sizeof(float) * N * 8);
    float* ald     = (float*)alloc(sizeof(float) * N * 8);
    float* wbuf    = (float*)alloc(sizeof(float) * (size_t)ET * 8);
    float* invb    = (float*)alloc(sizeof(float) * N * 8);
    unsigned short* hb16 = (unsigned short*)alloc(sizeof(unsigned short) * (size_t)N * 256);
    unsigned short* ab16 = (unsigned short*)alloc(sizeof(unsigned short) * (size_t)N * 256);
    unsigned short* wb1h = (unsigned short*)alloc(sizeof(unsigned short) * 128 * 256);
    unsigned short* wb1l = (unsigned short*)alloc(sizeof(unsigned short) * 128 * 256);
    unsigned short* wb2h = (unsigned short*)alloc(sizeof(unsigned short) * 256 * 256);
    unsigned short* wb2l = (unsigned short*)alloc(sizeof(unsigned short) * 256 * 256);
    unsigned short* wb3h = (unsigned short*)alloc(sizeof(unsigned short) * 128 * 256);
    unsigned short* wb3l = (unsigned short*)alloc(sizeof(unsigned short) * 128 * 256);
    (void)ws_size;

    const int nb = (N + 1023) / 1024;
    const int PG = 2048;   // persistent grid (8192 waves = full residency)

    // --- weight conversion (all layers, one launch, runs alongside CSR) ---
    convert_w_all_k<<<(R1 + R2 + R3 + 255) / 256, 256, 0, stream>>>(
        W1, W2, W3, wb1h, wb1l, wb2h, wb2l, wb3h, wb3l);

    // --- CSR build ---
    hipMemsetAsync(pos, 0, sizeof(int) * N, stream);
    count_edges_k<<<(ET + 255) / 256, 256, 0, stream>>>(ei, E, N, pos);
    scan1_k<<<nb, 256, 0, stream>>>(pos, row_ptr, bsums, N);
    scan2_k<<<1, 64, 0, stream>>>(bsums, nb);
    scan3_k<<<(N + 1 + 255) / 256, 256, 0, stream>>>(row_ptr, pos, bsums, N, ET);
    scatter_edges_k<<<(ET + 255) / 256, 256, 0, stream>>>(ei, E, N, pos, srcs);

    const int gy = (N + 127) / 128;
    const int gagg = (N + 3) / 4;
    const int gsm = (N * 8 + 255) / 256;

    // --- layer 1: x[N,128] @ W1[128,256] (fp32-A split, 3 products) -> bf16 h ---
    mfma_gemm_k<<<dim3(2, gy), 256, 0, stream>>>(x, wb1h, wb1l, hb16, N, 128, 256);
    compute_al_k<<<PG, 256, 0, stream>>>(hb16, as1, ad1, als, ald, N);
    edge_softmax_k<<<gsm, 256, 0, stream>>>(als, ald, row_ptr, srcs, wbuf, invb, N * 8);
    gat_gather_k<true><<<PG, 256, 0, stream>>>(hb16, wbuf, invb, row_ptr, srcs, b1, ab16, N);

    // --- layer 2: ab16[N,256] @ W2[256,256] (bf16-A, 2 products) ---
    gemm_bf16a_k<<<dim3(2, gy), 256, 0, stream>>>(ab16, wb2h, wb2l, hb16, N, 256, 256);
    compute_al_k<<<PG, 256, 0, stream>>>(hb16, as2, ad2, als, ald, N);
    edge_softmax_k<<<gsm, 256, 0, stream>>>(als, ald, row_ptr, srcs, wbuf, invb, N * 8);
    gat_gather_k<true><<<PG, 256, 0, stream>>>(hb16, wbuf, invb, row_ptr, srcs, b2, ab16, N);

    // --- layer 3: ab16[N,256] @ W3[256,40->128] -> h3 [N,128] bf16 ---
    gemm_bf16a_k<<<dim3(1, gy), 256, 0, stream>>>(ab16, wb3h, wb3l, hb16, N, 256, 128);
    compute_al3_k<<<gagg, 256, 0, stream>>>(hb16, as3, ad3, als, ald, N);
    edge_softmax3_k<<<(N + 255) / 256, 256, 0, stream>>>(als, ald, row_ptr, srcs, wbuf, invb, N);
    gat_gather3_k<<<PG, 256, 0, stream>>>(hb16, wbuf, invb, row_ptr, srcs, b3, (float*)d_out, N);
}